// Round 10
// baseline (655.130 us; speedup 1.0000x reference)
//
#include <hip/hip_runtime.h>
#include <hip/hip_bf16.h>
#include <math.h>

#define NSEQ 16
#define SEQ 256
#define H 768
#define NH 12
#define DKH 64
#define DI 4096
#define MROWS (NSEQ*SEQ)   // 4096
#define QKVN (3*H)         // 2304

typedef __bf16 v8bf __attribute__((ext_vector_type(8)));
typedef float  v4f  __attribute__((ext_vector_type(4)));
typedef short  v8s  __attribute__((ext_vector_type(8)));

__device__ inline unsigned short bf16b(float f) {
  __hip_bfloat16 h = __float2bfloat16(f);
  return *reinterpret_cast<unsigned short*>(&h);
}
__device__ inline float b2f(unsigned short b) {
  return __uint_as_float(((unsigned int)b) << 16);
}

__device__ __forceinline__ void gload16(const void* g, void* l) {
  __builtin_amdgcn_global_load_lds((const __attribute__((address_space(1))) void*)g,
                                   (__attribute__((address_space(3))) void*)l, 16, 0, 0);
}

__device__ __forceinline__ void waitvm(int n) {
  switch (n) {
    case 0:  asm volatile("s_waitcnt vmcnt(0)" ::: "memory"); break;
    case 2:  asm volatile("s_waitcnt vmcnt(2)" ::: "memory"); break;
    case 4:  asm volatile("s_waitcnt vmcnt(4)" ::: "memory"); break;
    case 8:  asm volatile("s_waitcnt vmcnt(8)" ::: "memory"); break;
    case 12: asm volatile("s_waitcnt vmcnt(12)" ::: "memory"); break;
    case 16: asm volatile("s_waitcnt vmcnt(16)" ::: "memory"); break;
    default: asm volatile("s_waitcnt vmcnt(0)" ::: "memory"); break;
  }
}

enum { MODE_F32_BIAS=0, MODE_BF16_BIAS=1, MODE_BF16_BIAS_RELU=2, MODE_SCORES=3, MODE_PV=4, MODE_F32_NOBIAS=5 };

// ================= bf16 MFMA GEMM (4 waves), BK parameterized =================
template<int BM, int BN, int MODE, int BK, int DEPTH, bool SWZ>
__global__ __launch_bounds__(256) void k_mm(
    const unsigned short* __restrict__ A, int lda, long long saN, long long saH,
    const unsigned short* __restrict__ B, int ldb, long long sbN, long long sbH,
    void* __restrict__ Cout, int ldc, long long scN, long long scH,
    const float* __restrict__ bias, int K, int nhdiv) {
  constexpr int MI = BM/32, NI = BN/32;
  constexpr int CH  = BK/8;
  constexpr int RPC = 512/BK;
  constexpr int SW  = CH - 1;
  constexpr int SSH = (BK == 32) ? 1 : 0;
  constexpr int AISS = BM*BK/2048, BISS = BN*BK/2048;
  constexpr int LPT = AISS + BISS;
  constexpr int TA = BM*BK, TB = BN*BK;
  __shared__ unsigned short As[DEPTH*TA];
  __shared__ unsigned short Bs[DEPTH*TB];
  int t = threadIdx.x;
  int z = blockIdx.z, n = z / nhdiv, h = z - n*nhdiv;
  int lane = t & 63, wid = t >> 6, wr = wid >> 1, wc = wid & 1;

  int bx = blockIdx.x, by = blockIdx.y;
  if (SWZ) {
    int gx = gridDim.x;
    int nwg = gx * gridDim.y;
    int lin = by*gx + bx;
    int q = nwg >> 3, r = nwg & 7;
    int xcd = lin & 7, idx = lin >> 3;
    int swz = (xcd < r) ? (xcd*(q+1) + idx) : (r*(q+1) + (xcd-r)*q + idx);
    bx = swz % gx; by = swz / gx;
  }

  const unsigned short* Ab = A + (size_t)n*saN + (size_t)h*saH + (size_t)by*BM*lda;
  const unsigned short* Bb = B + (size_t)n*sbN + (size_t)h*sbH + (size_t)bx*BN*ldb;

  const unsigned short* aSrc[AISS]; int aOff[AISS];
#pragma unroll
  for (int r = 0; r < AISS; ++r) {
    int chunk = wid*AISS + r;
    int row = chunk*RPC + lane/CH;
    int col = ((lane % CH) ^ ((row >> SSH) & SW)) * 8;
    aSrc[r] = Ab + (size_t)row*lda + col;
    aOff[r] = chunk*512;
  }
  const unsigned short* bSrc[BISS]; int bOff[BISS];
#pragma unroll
  for (int r = 0; r < BISS; ++r) {
    int chunk = wid*BISS + r;
    int row = chunk*RPC + lane/CH;
    int col = ((lane % CH) ^ ((row >> SSH) & SW)) * 8;
    bSrc[r] = Bb + (size_t)row*ldb + col;
    bOff[r] = chunk*512;
  }

  v4f acc[MI][NI];
#pragma unroll
  for (int i = 0; i < MI; ++i)
#pragma unroll
    for (int j = 0; j < NI; ++j) acc[i][j] = (v4f){0.f,0.f,0.f,0.f};

  auto issue = [&](int tt, int buf) {
    int k0 = tt * BK;
#pragma unroll
    for (int r = 0; r < AISS; ++r) gload16(aSrc[r] + k0, &As[buf*TA + aOff[r]]);
#pragma unroll
    for (int r = 0; r < BISS; ++r) gload16(bSrc[r] + k0, &Bs[buf*TB + bOff[r]]);
  };

  int nt = K / BK;
  for (int p = 0; p < DEPTH-1 && p < nt; ++p) issue(p, p);
  int cbuf = 0;
  int ibuf = (DEPTH-1) % DEPTH;
  for (int tt = 0; tt < nt; ++tt) {
    int ahead = tt + DEPTH - 1;
    if (ahead < nt) {
      issue(ahead, ibuf);
      waitvm((DEPTH-1)*LPT);
    } else {
      waitvm((nt-1-tt)*LPT);
    }
    __builtin_amdgcn_s_barrier();
    asm volatile("" ::: "memory");
#pragma unroll
    for (int ks = 0; ks < BK/32; ++ks) {
      v8bf af[MI], bfr[NI];
#pragma unroll
      for (int i = 0; i < MI; ++i) {
        int row = wr*(BM/2) + i*16 + (lane & 15);
        int c = (ks*4 + (lane >> 4)) ^ ((row >> SSH) & SW);
        af[i] = *(const v8bf*)&As[cbuf*TA + row*BK + c*8];
      }
#pragma unroll
      for (int j = 0; j < NI; ++j) {
        int row = wc*(BN/2) + j*16 + (lane & 15);
        int c = (ks*4 + (lane >> 4)) ^ ((row >> SSH) & SW);
        bfr[j] = *(const v8bf*)&Bs[cbuf*TB + row*BK + c*8];
      }
#pragma unroll
      for (int i = 0; i < MI; ++i)
#pragma unroll
        for (int j = 0; j < NI; ++j)
          acc[i][j] = __builtin_amdgcn_mfma_f32_16x16x32_bf16(af[i], bfr[j], acc[i][j], 0, 0, 0);
    }
    asm volatile("s_waitcnt lgkmcnt(0)" ::: "memory");
    __builtin_amdgcn_s_barrier();
    asm volatile("" ::: "memory");
    cbuf = (cbuf + 1 == DEPTH) ? 0 : cbuf + 1;
    ibuf = (ibuf + 1 == DEPTH) ? 0 : ibuf + 1;
  }

  float* Cf = (float*)Cout;
  unsigned short* Ch = (unsigned short*)Cout;
  size_t cb = (size_t)n*scN + (size_t)h*scH;
  int grow0 = by*BM + wr*(BM/2);
  int gcol0 = bx*BN + wc*(BN/2);
#pragma unroll
  for (int i = 0; i < MI; ++i) {
#pragma unroll
    for (int j = 0; j < NI; ++j) {
      int col = gcol0 + j*16 + (lane & 15);
      float bval = 0.f;
      if (MODE == MODE_F32_BIAS || MODE == MODE_BF16_BIAS || MODE == MODE_BF16_BIAS_RELU)
        bval = bias[col];
#pragma unroll
      for (int r = 0; r < 4; ++r) {
        int row = grow0 + i*16 + (lane>>4)*4 + r;
        float v = acc[i][j][r];
        if (MODE == MODE_F32_BIAS) {
          Cf[cb + (size_t)row*ldc + col] = v + bval;
        } else if (MODE == MODE_F32_NOBIAS) {
          Cf[cb + (size_t)row*ldc + col] = v;
        } else if (MODE == MODE_PV) {
          Ch[cb + (size_t)row*ldc + col] = bf16b(v);
        } else {
          v += bval;
          if (MODE == MODE_BF16_BIAS_RELU) v = fmaxf(v, 0.f);
          Ch[cb + (size_t)row*ldc + col] = bf16b(v);
        }
      }
    }
  }
}

// ========== 256x256 / 8-wave / BK64, 4-quadrant-phase pipelined GEMM ==========
// Phases per K-tile: q=(ks, j-half). Each phase: {issue 2 gloads of tile tt+1
// into other buf} + {10 ds_read_b128} + lgkmcnt(0) + sched_barrier + setprio'd
// 16 MFMA. Counted vmcnt(2) + barrier only at q0; WAR barrier at q3.
template<int MODE>
__global__ __launch_bounds__(512) void k_mm256p8(
    const unsigned short* __restrict__ A, int lda,
    const unsigned short* __restrict__ B, int ldb,
    void* __restrict__ Cout, int ldc,
    const float* __restrict__ bias, int K) {
  extern __shared__ __align__(16) unsigned short smem[];
  unsigned short* As = smem;            // [2][256*64]
  unsigned short* Bs = smem + 2*16384;  // [2][256*64]
  constexpr int TT = 256*64;
  int t = threadIdx.x, lane = t & 63, wid = t >> 6;
  int wr = wid >> 2, wc = wid & 3;

  int bx = blockIdx.x, by = blockIdx.y;
  {
    int gx = gridDim.x, nwg = gx * gridDim.y;
    int lin = by*gx + bx;
    int q = nwg >> 3, r = nwg & 7;
    int xcd = lin & 7, idx = lin >> 3;
    int swz = (xcd < r) ? (xcd*(q+1) + idx) : (r*(q+1) + (xcd-r)*q + idx);
    bx = swz % gx; by = swz / gx;
  }

  const unsigned short* Ab = A + (size_t)by*256*lda;
  const unsigned short* Bb = B + (size_t)bx*256*ldb;

  const unsigned short* aSrc[4]; int aOff[4];
  const unsigned short* bSrc[4]; int bOff[4];
#pragma unroll
  for (int r = 0; r < 4; ++r) {
    int chunk = wid*4 + r;
    int row = chunk*8 + (lane >> 3);
    int col = ((lane & 7) ^ (row & 7)) * 8;
    aSrc[r] = Ab + (size_t)row*lda + col;
    bSrc[r] = Bb + (size_t)row*ldb + col;
    aOff[r] = chunk*512;
    bOff[r] = chunk*512;
  }

  v4f acc[8][4];
#pragma unroll
  for (int i = 0; i < 8; ++i)
#pragma unroll
    for (int j = 0; j < 4; ++j) acc[i][j] = (v4f){0.f,0.f,0.f,0.f};

  auto issueAB = [&](int tt, int buf, int q) {
    int k0 = tt << 6;
    gload16(aSrc[q] + k0, &As[buf*TT + aOff[q]]);
    gload16(bSrc[q] + k0, &Bs[buf*TT + bOff[q]]);
  };

  int nt = K >> 6;
  // prologue: tile 0 -> buf 0 (8 gloads)
#pragma unroll
  for (int q = 0; q < 4; ++q) issueAB(0, 0, q);

  for (int tt = 0; tt < nt; ++tt) {
    int cur = tt & 1, nxt = cur ^ 1;
    bool more = (tt + 1 < nt);
#pragma unroll
    for (int q = 0; q < 4; ++q) {
      if (q == 0) {
        if (more) issueAB(tt+1, nxt, 0);
        waitvm(more ? 2 : 0);          // tile tt's 8 loads retired; 2 newest in flight
        __builtin_amdgcn_s_barrier();  // all waves: buf[cur] ready
        asm volatile("" ::: "memory");
      } else {
        if (more) issueAB(tt+1, nxt, q);
      }
      int ks = q & 1, jh = q >> 1;
      v8bf af[8], bfr[2];
#pragma unroll
      for (int i = 0; i < 8; ++i) {
        int row = wr*128 + i*16 + (lane & 15);
        int c = (ks*4 + (lane >> 4)) ^ (row & 7);
        af[i] = *(const v8bf*)&As[cur*TT + row*64 + c*8];
      }
#pragma unroll
      for (int jj = 0; jj < 2; ++jj) {
        int row = wc*64 + (jh*2 + jj)*16 + (lane & 15);
        int c = (ks*4 + (lane >> 4)) ^ (row & 7);
        bfr[jj] = *(const v8bf*)&Bs[cur*TT + row*64 + c*8];
      }
      asm volatile("s_waitcnt lgkmcnt(0)" ::: "memory");
      __builtin_amdgcn_sched_barrier(0);          // rule 18: pin MFMA after wait
      __builtin_amdgcn_s_setprio(1);
#pragma unroll
      for (int i = 0; i < 8; ++i)
#pragma unroll
        for (int jj = 0; jj < 2; ++jj)
          acc[i][jh*2+jj] = __builtin_amdgcn_mfma_f32_16x16x32_bf16(af[i], bfr[jj], acc[i][jh*2+jj], 0, 0, 0);
      __builtin_amdgcn_s_setprio(0);
      if (q == 3) {
        __builtin_amdgcn_s_barrier();  // WAR: all reads of buf[cur] done before tt+1 stages tt+2 into it
        asm volatile("" ::: "memory");
      }
    }
  }

  float* Cf = (float*)Cout;
  unsigned short* Ch = (unsigned short*)Cout;
  int grow0 = by*256 + wr*128;
  int gcol0 = bx*256 + wc*64;
#pragma unroll
  for (int i = 0; i < 8; ++i) {
#pragma unroll
    for (int j = 0; j < 4; ++j) {
      int col = gcol0 + j*16 + (lane & 15);
      float bval = 0.f;
      if (MODE == MODE_F32_BIAS || MODE == MODE_BF16_BIAS || MODE == MODE_BF16_BIAS_RELU)
        bval = bias[col];
#pragma unroll
      for (int r = 0; r < 4; ++r) {
        int row = grow0 + i*16 + (lane>>4)*4 + r;
        float v = acc[i][j][r];
        if (MODE == MODE_F32_BIAS) {
          Cf[(size_t)row*ldc + col] = v + bval;
        } else if (MODE == MODE_F32_NOBIAS) {
          Cf[(size_t)row*ldc + col] = v;
        } else {
          v += bval;
          if (MODE == MODE_BF16_BIAS_RELU) v = fmaxf(v, 0.f);
          Ch[(size_t)row*ldc + col] = bf16b(v);
        }
      }
    }
  }
}

// ============ fused QK^T + scale + bias(bf16) + row-softmax -> P bf16 ============
__global__ __launch_bounds__(256) void k_qksm(
    const unsigned short* __restrict__ qkv,
    const unsigned short* __restrict__ biasb,
    unsigned short* __restrict__ P) {
  __shared__ unsigned short Qs[64*64];
  __shared__ unsigned short Ks[256*64];
  int t = threadIdx.x, lane = t & 63, wid = t >> 6;
  int z = blockIdx.y, n = z / NH, h = z - n*NH;
  int m0 = blockIdx.x * 64;
  const unsigned short* Qb = qkv + (size_t)n*SEQ*QKVN + (size_t)h*DKH + (size_t)m0*QKVN;
  const unsigned short* Kb = qkv + (size_t)n*SEQ*QKVN + H + (size_t)h*DKH;
#pragma unroll
  for (int r = 0; r < 2; ++r) {
    int chunk = wid*2 + r;
    int row = chunk*8 + (lane >> 3);
    int col = ((lane & 7) ^ (row & 7)) * 8;
    gload16(Qb + (size_t)row*QKVN + col, &Qs[chunk*512]);
  }
#pragma unroll
  for (int r = 0; r < 8; ++r) {
    int chunk = wid*8 + r;
    int row = chunk*8 + (lane >> 3);
    int col = ((lane & 7) ^ (row & 7)) * 8;
    gload16(Kb + (size_t)row*QKVN + col, &Ks[chunk*512]);
  }
  __syncthreads();
  v4f acc[16];
#pragma unroll
  for (int j = 0; j < 16; ++j) acc[j] = (v4f){0.f,0.f,0.f,0.f};
#pragma unroll
  for (int ks = 0; ks < 2; ++ks) {
    int arow = wid*16 + (lane & 15);
    int ac = (ks*4 + (lane >> 4)) ^ (arow & 7);
    v8bf af = *(const v8bf*)&Qs[arow*64 + ac*8];
#pragma unroll
    for (int j = 0; j < 16; ++j) {
      int brow = j*16 + (lane & 15);
      int bc = (ks*4 + (lane >> 4)) ^ (brow & 7);
      v8bf bf = *(const v8bf*)&Ks[brow*64 + bc*8];
      acc[j] = __builtin_amdgcn_mfma_f32_16x16x32_bf16(af, bf, acc[j], 0, 0, 0);
    }
  }
  int col = lane & 15, quad = lane >> 4;
  const unsigned short* bb = biasb + (size_t)n*65536;
  float e[16][4];
  float rm[4] = {-1e30f, -1e30f, -1e30f, -1e30f};
#pragma unroll
  for (int r = 0; r < 4; ++r) {
    int row = m0 + wid*16 + quad*4 + r;
#pragma unroll
    for (int j = 0; j < 16; ++j) {
      float v = acc[j][r]*0.125f + b2f(bb[(size_t)row*256 + j*16 + col]);
      e[j][r] = v;
      rm[r] = fmaxf(rm[r], v);
    }
  }
#pragma unroll
  for (int r = 0; r < 4; ++r)
#pragma unroll
    for (int m = 1; m < 16; m <<= 1) rm[r] = fmaxf(rm[r], __shfl_xor(rm[r], m, 64));
  float rs[4] = {0.f, 0.f, 0.f, 0.f};
#pragma unroll
  for (int r = 0; r < 4; ++r)
#pragma unroll
    for (int j = 0; j < 16; ++j) {
      float ev = __expf(e[j][r] - rm[r]);
      e[j][r] = ev;
      rs[r] += ev;
    }
#pragma unroll
  for (int r = 0; r < 4; ++r) {
#pragma unroll
    for (int m = 1; m < 16; m <<= 1) rs[r] += __shfl_xor(rs[r], m, 64);
    rs[r] = 1.0f/rs[r];
  }
  unsigned short* Pz = P + (size_t)z*65536;
#pragma unroll
  for (int r = 0; r < 4; ++r) {
    int row = m0 + wid*16 + quad*4 + r;
#pragma unroll
    for (int j = 0; j < 16; ++j)
      Pz[(size_t)row*256 + j*16 + col] = bf16b(e[j][r]*rs[r]);
  }
}

// ============ weight transpose+cast ============
__global__ __launch_bounds__(256) void k_wT(const float* __restrict__ in,
                                            unsigned short* __restrict__ out,
                                            int Nn, int Kk) {
  int n0 = blockIdx.x*64, k0 = blockIdx.y*64;
  __shared__ float T[64][72];
  int t = threadIdx.x;
  int r = t >> 4, c4 = (t & 15) * 4;
#pragma unroll
  for (int i = 0; i < 4; ++i) {
    float4 v = *(const float4*)(in + (size_t)(k0 + r + i*16)*Nn + n0 + c4);
    T[c4+0][r+i*16] = v.x; T[c4+1][r+i*16] = v.y;
    T[c4+2][r+i*16] = v.z; T[c4+3][r+i*16] = v.w;
  }
  __syncthreads();
  int c = t >> 3, r8 = (t & 7) * 8;
#pragma unroll
  for (int i = 0; i < 2; ++i) {
    int cc = c + i*32;
    v8s o;
#pragma unroll
    for (int j = 0; j < 8; ++j) o[j] = (short)bf16b(T[cc][r8+j]);
    *(v8s*)(out + (size_t)(n0+cc)*Kk + k0 + r8) = o;
  }
}

__global__ void k_bqkv(const float* __restrict__ bq, const float* __restrict__ bk,
                       const float* __restrict__ bv, float* __restrict__ o) {
  int i = blockIdx.x*256 + threadIdx.x;
  if (i >= 3*QKVN) return;
  int l = i / QKVN, j = i - l*QKVN;
  float v = (j < H) ? bq[l*H + j] : (j < 2*H) ? bk[l*H + j - H] : bv[l*H + j - 2*H];
  o[i] = v;
}

__global__ __launch_bounds__(256) void k_cast(const float* __restrict__ x,
                                              float* __restrict__ enc,
                                              unsigned short* __restrict__ enc16) {
  size_t i = ((size_t)blockIdx.x*256 + threadIdx.x)*4;
  float4 v = *(const float4*)(x + i);
  *(float4*)(enc + i) = v;
  ushort4 u = { bf16b(v.x), bf16b(v.y), bf16b(v.z), bf16b(v.w) };
  *(ushort4*)(enc16 + i) = u;
}

__global__ __launch_bounds__(256) void k_vT(const unsigned short* __restrict__ qkv,
                                            unsigned short* __restrict__ vT) {
  int z = blockIdx.x, n = z/NH, h = z - n*NH;
  const unsigned short* src = qkv + (size_t)n*SEQ*QKVN + 2*H + (size_t)h*DKH;
  __shared__ unsigned short tile[64][264];
  int t = threadIdx.x;
  int r0 = t >> 3, d0 = (t & 7) * 8;
#pragma unroll
  for (int i = 0; i < 8; ++i) {
    int r = r0 + i*32;
    v8s vv = *(const v8s*)(src + (size_t)r*QKVN + d0);
#pragma unroll
    for (int j = 0; j < 8; ++j) tile[d0+j][r] = (unsigned short)vv[j];
  }
  __syncthreads();
  int d = t >> 2, rb = (t & 3) * 64;
  unsigned short* dst = vT + (size_t)z*DKH*SEQ + (size_t)d*SEQ + rb;
#pragma unroll
  for (int i = 0; i < 8; ++i)
    *(v8s*)(dst + i*8) = *(const v8s*)&tile[d][rb + i*8];
}

__global__ __launch_bounds__(256) void k_fusion_weights(
    const float* __restrict__ x, const float* __restrict__ lin_w,
    const float* __restrict__ lin_b, float* __restrict__ wsoft) {
  int n = blockIdx.x, t = threadIdx.x;
  __shared__ float xm[H];
  __shared__ float sred[4];
  __shared__ float logits[12];
  if (t < 192) {
    const float4* p = (const float4*)(x + (size_t)n*SEQ*H) + t;
    float4 s = {0.f,0.f,0.f,0.f};
    for (int r = 0; r < SEQ; ++r) {
      float4 v = p[(size_t)r*192];
      s.x += v.x; s.y += v.y; s.z += v.z; s.w += v.w;
    }
    xm[t*4+0] = s.x*(1.0f/SEQ); xm[t*4+1] = s.y*(1.0f/SEQ);
    xm[t*4+2] = s.z*(1.0f/SEQ); xm[t*4+3] = s.w*(1.0f/SEQ);
  }
  __syncthreads();
  float lacc[12];
#pragma unroll
  for (int j = 0; j < 12; ++j) lacc[j] = 0.f;
  for (int hh = t; hh < H; hh += 256) {
    float xv = xm[hh];
#pragma unroll
    for (int j = 0; j < 12; ++j) lacc[j] += xv * lin_w[hh*12 + j];
  }
  for (int j = 0; j < 12; ++j) {
    float v = lacc[j];
#pragma unroll
    for (int m = 1; m < 64; m <<= 1) v += __shfl_xor(v, m, 64);
    if ((t & 63) == 0) sred[t >> 6] = v;
    __syncthreads();
    if (t == 0) logits[j] = sred[0]+sred[1]+sred[2]+sred[3] + lin_b[j];
    __syncthreads();
  }
  if (t < 3) {
    int l = t;
    float mx = -1e30f;
    for (int m = 0; m < 4; ++m) mx = fmaxf(mx, logits[l*4+m]);
    float e[4], s = 0.f;
    for (int m = 0; m < 4; ++m) { e[m] = expf(logits[l*4+m]-mx); s += e[m]; }
    for (int m = 0; m < 4; ++m) wsoft[(l*NSEQ + n)*4 + m] = e[m]/s;
  }
}

// mask fusion -> bf16 bias
__global__ __launch_bounds__(256) void k_bias(
    const float* __restrict__ cm, const float* __restrict__ dm,
    const float* __restrict__ ent, const float* __restrict__ sm,
    const float* __restrict__ wsoft, int l, unsigned short* __restrict__ bias) {
  int g = blockIdx.x*256 + threadIdx.x;
  int n = g >> 14;
  int k4 = g & 63;
  const float* w = wsoft + (l*NSEQ + n)*4;
  float w0 = w[0], w1 = w[1], w2 = w[2], w3 = w[3];
  float4 c = ((const float4*)cm)[g];
  float4 d = ((const float4*)dm)[g];
  float4 s = ((const float4*)sm)[g];
  float4 e = ((const float4*)(ent + (size_t)n*SEQ))[k4];
  ushort4 o;
  o.x = bf16b(w0*c.x + w1*d.x + w2*e.x + w3*s.x);
  o.y = bf16b(w0*c.y + w1*d.y + w2*e.y + w3*s.y);
  o.z = bf16b(w0*c.z + w1*d.z + w2*e.z + w3*s.z);
  o.w = bf16b(w0*c.w + w1*d.w + w2*e.w + w3*s.w);
  ((ushort4*)bias)[g] = o;
}

__global__ void k_nonpad(const int* __restrict__ ids, float* __restrict__ npad) {
  int i = blockIdx.x*256 + threadIdx.x;
  if (i < MROWS) npad[i] = (ids[i] != 1) ? 1.0f : 0.0f;
}

__global__ __launch_bounds__(256) void k_ln(
    const float* __restrict__ f, float* __restrict__ enc,
    unsigned short* __restrict__ enc16,
    const float* __restrict__ g, const float* __restrict__ b,
    const float* __restrict__ npad) {
  int r = blockIdx.x, t = threadIdx.x;
  size_t base = (size_t)r*H;
  float v0 = f[base+t]     + enc[base+t];
  float v1 = f[base+t+256] + enc[base+t+256];
  float v2 = f[base+t+512] + enc[base+t+512];
  __shared__ float sred[4];
  float s = v0+v1+v2;
#pragma unroll
  for (int m = 1; m < 64; m <<= 1) s += __shfl_xor(s, m, 64);
  if ((t & 63) == 0) sred[t >> 6] = s;
  __syncthreads();
  float mean = (sred[0]+sred[1]+sred[2]+sred[3]) * (1.0f/H);
  __syncthreads();
  float d0 = v0-mean, d1 = v1-mean, d2 = v2-mean;
  float ss = d0*d0 + d1*d1 + d2*d2;
#pragma unroll
  for (int m = 1; m < 64; m <<= 1) ss += __shfl_xor(ss, m, 64);
  if ((t & 63) == 0) sred[t >> 6] = ss;
  __syncthreads();
  float var = (sred[0]+sred[1]+sred[2]+sred[3]) * (1.0f/H);
  float rstd = 1.0f/sqrtf(var + 1e-5f);
  float npv = npad[r];
  float o0 = (g[t]    *d0*rstd + b[t]    )*npv;
  float o1 = (g[t+256]*d1*rstd + b[t+256])*npv;
  float o2 = (g[t+512]*d2*rstd + b[t+512])*npv;
  enc[base+t]     = o0; enc[base+t+256] = o1; enc[base+t+512] = o2;
  enc16[base+t]     = bf16b(o0);
  enc16[base+t+256] = bf16b(o1);
  enc16[base+t+512] = bf16b(o2);
}

__global__ __launch_bounds__(256) void k_ln4(
    const float* __restrict__ p, float* __restrict__ enc,
    unsigned short* __restrict__ enc16,
    const float* __restrict__ g, const float* __restrict__ b,
    const float* __restrict__ npad, const float* __restrict__ cbias) {
  int r = blockIdx.x, t = threadIdx.x;
  size_t base = (size_t)r*H;
  const size_t PS = (size_t)MROWS*H;
  float v0 = p[base+t]     + p[PS+base+t]     + p[2*PS+base+t]     + p[3*PS+base+t]     + cbias[t]     + enc[base+t];
  float v1 = p[base+t+256] + p[PS+base+t+256] + p[2*PS+base+t+256] + p[3*PS+base+t+256] + cbias[t+256] + enc[base+t+256];
  float v2 = p[base+t+512] + p[PS+base+t+512] + p[2*PS+base+t+512] + p[3*PS+base+t+512] + cbias[t+512] + enc[base+t+512];
  __shared__ float sred[4];
  float s = v0+v1+v2;
#pragma unroll
  for (int m = 1; m < 64; m <<= 1) s += __shfl_xor(s, m, 64);
  if ((t & 63) == 0) sred[t >> 6] = s;
  __syncthreads();
  float mean = (sred[0]+sred[1]+sred[2]+sred[3]) * (1.0f/H);
  __syncthreads();
  float d0 = v0-mean, d1 = v1-mean, d2 = v2-mean;
  float ss = d0*d0 + d1*d1 + d2*d2;
#pragma unroll
  for (int m = 1; m < 64; m <<= 1) ss += __shfl_xor(ss, m, 64);
  if ((t & 63) == 0) sred[t >> 6] = ss;
  __syncthreads();
  float var = (sred[0]+sred[1]+sred[2]+sred[3]) * (1.0f/H);
  float rstd = 1.0f/sqrtf(var + 1e-5f);
  float npv = npad[r];
  float o0 = (g[t]    *d0*rstd + b[t]    )*npv;
  float o1 = (g[t+256]*d1*rstd + b[t+256])*npv;
  float o2 = (g[t+512]*d2*rstd + b[t+512])*npv;
  enc[base+t]     = o0; enc[base+t+256] = o1; enc[base+t+512] = o2;
  enc16[base+t]     = bf16b(o0);
  enc16[base+t+256] = bf16b(o1);
  enc16[base+t+512] = bf16b(o2);
}

__global__ __launch_bounds__(256) void k_colstats(
    const float* __restrict__ enc, float* __restrict__ csum, float* __restrict__ csq) {
  int r0 = blockIdx.x*16, t = threadIdx.x;
  float s0=0,s1=0,s2=0,q0=0,q1=0,q2=0;
  for (int r = 0; r < 16; ++r) {
    const float* row = enc + (size_t)(r0+r)*H;
    float a = row[t], b = row[t+256], c = row[t+512];
    s0 += a; s1 += b; s2 += c;
    q0 += a*a; q1 += b*b; q2 += c*c;
  }
  atomicAdd(&csum[t],     s0); atomicAdd(&csum[t+256], s1); atomicAdd(&csum[t+512], s2);
  atomicAdd(&csq[t],      q0); atomicAdd(&csq[t+256],  q1); atomicAdd(&csq[t+512],  q2);
}

__global__ __launch_bounds__(256) void k_poolprep(
    const float* __restrict__ x, const float* __restrict__ enc,
    const float* __restrict__ csum, const float* __restrict__ csq,
    const float* __restrict__ bnt_g, const float* __restrict__ bnt_b,
    float* __restrict__ ps0) {
  int n = blockIdx.x, t = threadIdx.x;
  for (int hh = t; hh < H; hh += 256) {
    float m = csum[hh] * (1.0f/MROWS);
    float var = csq[hh] * (1.0f/MROWS) - m*m;
    float rstd = 1.0f/sqrtf(var + 1e-5f);
    float e = enc[(size_t)n*SEQ*H + hh];
    ps0[n*H + hh] = x[(size_t)n*SEQ*H + hh] + bnt_g[hh]*(e-m)*rstd + bnt_b[hh];
  }
}

__global__ __launch_bounds__(256) void k_poolmm(
    const float* __restrict__ ps0, const float* __restrict__ pool_w,
    const float* __restrict__ pool_b, float* __restrict__ pooled) {
  int n = blockIdx.y, jb = blockIdx.x*64;
  __shared__ float s0[H];
  __shared__ float part[4][64];
  int t = threadIdx.x;
  for (int hh = t; hh < H; hh += 256) s0[hh] = ps0[n*H + hh];
  __syncthreads();
  int j = t & 63, q = t >> 6;
  float a = 0.f;
  int h0 = q*192;
  for (int hh = h0; hh < h0+192; ++hh)
    a = fmaf(s0[hh], pool_w[(size_t)hh*H + jb + j], a);
  part[q][j] = a;
  __syncthreads();
  if (t < 64) {
    float v = part[0][t]+part[1][t]+part[2][t]+part[3][t] + pool_b[jb+t];
    pooled[n*H + jb + t] = tanhf(v);
  }
}

__global__ __launch_bounds__(256) void k_final(
    const float* __restrict__ pooled, const float* __restrict__ bn_g,
    const float* __restrict__ bn_b, const float* __restrict__ cls_w,
    const float* __restrict__ cls_b, float* __restrict__ out) {
  int t = threadIdx.x;
  float acc[16];
#pragma unroll
  for (int n = 0; n < 16; ++n) acc[n] = 0.f;
  for (int hh = t; hh < H; hh += 256) {
    float p[16]; float m = 0.f;
#pragma unroll
    for (int n = 0; n < 16; ++n) { p[n] = pooled[n*H + hh]; m += p[n]; }
    m *= (1.0f/16.f);
    float var = 0.f;
#pragma unroll
    for (int n = 0; n < 16; ++n) { float d = p[n]-m; var += d*d; }
    var *= (1.0f/16.f);
    float rstd = 1.0f/sqrtf(var + 1e-5f);
    float gw = bn_g[hh]*rstd*cls_w[hh];
    float off = bn_b[hh]*cls_w[hh];
#pragma unroll
    for (int n = 0; n < 16; ++n) acc[n] += (p[n]-m)*gw + off;
  }
  __shared__ float sred[4];
  for (int n = 0; n < 16; ++n) {
    float v = acc[n];
#pragma unroll
    for (int m = 1; m < 64; m <<= 1) v += __shfl_xor(v, m, 64);
    if ((t & 63) == 0) sred[t >> 6] = v;
    __syncthreads();
    if (t == 0) out[n] = sred[0]+sred[1]+sred[2]+sred[3] + cls_b[0];
    __syncthreads();
  }
}

extern "C" void kernel_launch(void* const* d_in, const int* in_sizes, int n_in,
                              void* d_out, int out_size, void* d_ws, size_t ws_size,
                              hipStream_t stream) {
  const int*   input_ids = (const int*)  d_in[0];
  const float* x       = (const float*)d_in[1];
  const float* cm      = (const float*)d_in[3];
  const float* dm      = (const float*)d_in[4];
  const float* ent     = (const float*)d_in[5];
  const float* sm      = (const float*)d_in[6];
  const float* lin_w   = (const float*)d_in[7];
  const float* lin_b   = (const float*)d_in[8];
  const float* Wq      = (const float*)d_in[9];
  const float* bq      = (const float*)d_in[10];
  const float* Wk      = (const float*)d_in[11];
  const float* bk      = (const float*)d_in[12];
  const float* Wv      = (const float*)d_in[13];
  const float* bv      = (const float*)d_in[14];
  const float* Wo      = (const float*)d_in[15];
  const float* bo      = (const float*)d_in[16];
  const float* ln1_g   = (const float*)d_in[17];
  const float* ln1_b   = (const float*)d_in[18];
  const float* W1      = (const float*)d_in[19];
  const float* b1      = (const float*)d_in[20];
  const float* W2      = (const float*)d_in[21];
  const float* b2      = (const float*)d_in[22];
  const float* ln2_g   = (const float*)d_in[23];
  const float* ln2_b   = (const float*)d_in[24];
  const float* bnt_g   = (const float*)d_in[25];
  const float* bnt_b   = (const float*)d_in[26];
  const float* pool_w  = (const float*)d_in[27];
  const float* pool_b  = (const float*)d_in[28];
  const float* bn_g    = (const float*)d_in[29];
  const float* bn_b    = (const float*)d_in[30];
  const float* cls_w   = (const float*)d_in[31];
  const float* cls_b   = (const float*)d_in[32];
  float* out = (float*)d_out;
  (void)ws_size; (void)n_in; (void)in_sizes; (void)out_size;

  char* wsb = (char*)d_ws;
  size_t off = 0;
  auto alloc = [&](size_t bytes) {
    void* p = (void*)(wsb + off);
    off += (bytes + 255) & ~(size_t)255;
    return p;
  };
  float* enc            = (float*)alloc((size_t)MROWS*H*4);
  unsigned short* enc16 = (unsigned short*)alloc((size_t)MROWS*H*2);
  unsigned short* qkv16 = (unsigned short*)alloc((size_t)MROWS*QKVN*2);
  unsigned short* vT    = (unsigned short*)alloc((size_t)192*DKH*SEQ*2);
  unsigned short* ob16  = (unsigned short*)alloc((size_t)MROWS*H*2);
  float* fbuf           = (float*)alloc((size_t)4*MROWS*H*4);
  unsigned short* PH    = (unsigned short*)alloc((size_t)MROWS*DI*2);
  unsigned short* P16     = PH;
  unsigned short* hidden16 = PH;
  unsigned short* biasb = (unsigned short*)alloc((size_t)NSEQ*SEQ*SEQ*2);
  unsigned short* WqkvT = (unsigned short*)alloc((size_t)3*QKVN*H*2);
  unsigned short* WoT   = (unsigned short*)alloc((size_t)3*H*H*2);
  unsigned short* W1T   = (unsigned short*)alloc((size_t)3*DI*H*2);
  unsigned short* W2T   = (unsigned short*)alloc((size_t)3*H*DI*2);
  float* bqkv   = (float*)alloc(3*QKVN*4);
  float* wsoft  = (float*)alloc(3*16*4*4);
  float* npad   = (float*)alloc(MROWS*4);
  float* csum   = (float*)alloc(H*4);
  float* csq    = (float*)alloc(H*4);
  float* ps0    = (float*)alloc(16*H*4);
  float* pooled = (float*)alloc(16*H*4);

  k_cast<<<MROWS*H/1024, 256, 0, stream>>>(x, enc, enc16);
  k_fusion_weights<<<16, 256, 0, stream>>>(x, lin_w, lin_b, wsoft);
  k_nonpad<<<MROWS/256, 256, 0, stream>>>(input_ids, npad);
  k_bqkv<<<27, 256, 0, stream>>>(bq, bk, bv, bqkv);
  for (int l = 0; l < 3; ++l) {
    k_wT<<<dim3(12,12), 256, 0, stream>>>(Wq + (size_t)l*H*H, WqkvT + (size_t)l*QKVN*H,           H, H);
    k_wT<<<dim3(12,12), 256, 0, stream>>>(Wk + (size_t)l*H*H, WqkvT + (size_t)l*QKVN*H + H*H,     H, H);
    k_wT<<<dim3(12,12), 256, 0, stream>>>(Wv + (size_t)l*H*H, WqkvT + (size_t)l*QKVN*H + 2*H*H,   H, H);
    k_wT<<<dim3(12,12), 256, 0, stream>>>(Wo + (size_t)l*H*H, WoT + (size_t)l*H*H,                H, H);
    k_wT<<<dim3(64,12), 256, 0, stream>>>(W1 + (size_t)l*H*DI, W1T + (size_t)l*DI*H,              DI, H);
    k_wT<<<dim3(12,64), 256, 0, stream>>>(W2 + (size_t)l*DI*H, W2T + (size_t)l*H*DI,              H, DI);
  }

  for (int l = 0; l < 3; ++l) {
    k_bias<<<1024, 256, 0, stream>>>(cm, dm, ent, sm, wsoft, l, biasb);
    // QKV: 128x128, BK=32, depth-2 counted
    k_mm<128,128,MODE_BF16_BIAS,32,2,true><<<dim3(18,32,1), 256, 0, stream>>>(
        enc16, H, 0, 0, WqkvT + (size_t)l*QKVN*H, H, 0, 0,
        qkv16, QKVN, 0, 0, bqkv + l*QKVN, H, 1);
    // fused QK^T + scale + bias(bf16) + softmax -> P bf16
    k_qksm<<<dim3(4,192), 256, 0, stream>>>(qkv16, biasb, P16);
    k_vT<<<192, 256, 0, stream>>>(qkv16, vT);
    // PV (BK=64 depth-3)
    k_mm<64,64,MODE_PV,64,3,false><<<dim3(1,4,192), 256, 0, stream>>>(
        P16, SEQ, (long long)NH*SEQ*SEQ, (long long)SEQ*SEQ,
        vT, SEQ, (long long)NH*DKH*SEQ, (long long)DKH*SEQ,
        ob16, H, (long long)SEQ*H, DKH,
        nullptr, SEQ, NH);
    // Wo (64x64 BK=32 depth-2 + swizzle)
    k_mm<64,64,MODE_F32_BIAS,32,2,true><<<dim3(12,64,1), 256, 0, stream>>>(
        ob16, H, 0, 0, WoT + (size_t)l*H*H, H, 0, 0,
        fbuf, H, 0, 0, bo + l*H, H, 1);
    k_ln<<<MROWS, 256, 0, stream>>>(fbuf, enc, enc16, ln1_g + l*H, ln1_b + l*H, npad);
    // W1 + ReLU: 256x256 8-wave 4-quadrant-phase pipeline, grid 16x16
    k_mm256p8<MODE_BF16_BIAS_RELU><<<dim3(16,16), 512, 131072, stream>>>(
        enc16, H, W1T + (size_t)l*DI*H, H, hidden16, DI, b1 + l*DI, H);
    // W2: split-K4, 128x128, BK=32, depth-2 counted
    k_mm<128,128,MODE_F32_NOBIAS,32,2,true><<<dim3(6,32,4), 256, 0, stream>>>(
        hidden16, DI, 0, 1024, W2T + (size_t)l*H*DI, DI, 0, 1024,
        fbuf, H, 0, (long long)MROWS*H, nullptr, 1024, 4);
    k_ln4<<<MROWS, 256, 0, stream>>>(fbuf, enc, enc16, ln2_g + l*H, ln2_b + l*H, npad, b2 + l*H);
  }

  hipMemsetAsync(csum, 0, H*sizeof(float), stream);
  hipMemsetAsync(csq,  0, H*sizeof(float), stream);
  k_colstats<<<256, 256, 0, stream>>>(enc, csum, csq);
  k_poolprep<<<16, 256, 0, stream>>>(x, enc, csum, csq, bnt_g, bnt_b, ps0);
  k_poolmm<<<dim3(12,16), 256, 0, stream>>>(ps0, pool_w, pool_b, pooled);
  k_final<<<1, 256, 0, stream>>>(pooled, bn_g, bn_b, cls_w, cls_b, out);
}

// Round 11
// 643.062 us; speedup vs baseline: 1.0188x; 1.0188x over previous
//
#include <hip/hip_runtime.h>
#include <hip/hip_bf16.h>
#include <math.h>

#define NSEQ 16
#define SEQ 256
#define H 768
#define NH 12
#define DKH 64
#define DI 4096
#define MROWS (NSEQ*SEQ)   // 4096
#define QKVN (3*H)         // 2304

typedef __bf16 v8bf __attribute__((ext_vector_type(8)));
typedef float  v4f  __attribute__((ext_vector_type(4)));
typedef short  v8s  __attribute__((ext_vector_type(8)));

__device__ inline unsigned short bf16b(float f) {
  __hip_bfloat16 h = __float2bfloat16(f);
  return *reinterpret_cast<unsigned short*>(&h);
}
__device__ inline float b2f(unsigned short b) {
  return __uint_as_float(((unsigned int)b) << 16);
}

__device__ __forceinline__ void gload16(const void* g, void* l) {
  __builtin_amdgcn_global_load_lds((const __attribute__((address_space(1))) void*)g,
                                   (__attribute__((address_space(3))) void*)l, 16, 0, 0);
}

__device__ __forceinline__ void waitvm(int n) {
  switch (n) {
    case 0:  asm volatile("s_waitcnt vmcnt(0)" ::: "memory"); break;
    case 2:  asm volatile("s_waitcnt vmcnt(2)" ::: "memory"); break;
    case 4:  asm volatile("s_waitcnt vmcnt(4)" ::: "memory"); break;
    case 8:  asm volatile("s_waitcnt vmcnt(8)" ::: "memory"); break;
    case 12: asm volatile("s_waitcnt vmcnt(12)" ::: "memory"); break;
    case 16: asm volatile("s_waitcnt vmcnt(16)" ::: "memory"); break;
    default: asm volatile("s_waitcnt vmcnt(0)" ::: "memory"); break;
  }
}

enum { MODE_F32_BIAS=0, MODE_BF16_BIAS=1, MODE_BF16_BIAS_RELU=2, MODE_SCORES=3, MODE_PV=4, MODE_F32_NOBIAS=5 };

// ================= bf16 MFMA GEMM (4 waves), BK parameterized =================
template<int BM, int BN, int MODE, int BK, int DEPTH, bool SWZ>
__global__ __launch_bounds__(256) void k_mm(
    const unsigned short* __restrict__ A, int lda, long long saN, long long saH,
    const unsigned short* __restrict__ B, int ldb, long long sbN, long long sbH,
    void* __restrict__ Cout, int ldc, long long scN, long long scH,
    const float* __restrict__ bias, int K, int nhdiv) {
  constexpr int MI = BM/32, NI = BN/32;
  constexpr int CH  = BK/8;
  constexpr int RPC = 512/BK;
  constexpr int SW  = CH - 1;
  constexpr int SSH = (BK == 32) ? 1 : 0;
  constexpr int AISS = BM*BK/2048, BISS = BN*BK/2048;
  constexpr int LPT = AISS + BISS;
  constexpr int TA = BM*BK, TB = BN*BK;
  __shared__ unsigned short As[DEPTH*TA];
  __shared__ unsigned short Bs[DEPTH*TB];
  int t = threadIdx.x;
  int z = blockIdx.z, n = z / nhdiv, h = z - n*nhdiv;
  int lane = t & 63, wid = t >> 6, wr = wid >> 1, wc = wid & 1;

  int bx = blockIdx.x, by = blockIdx.y;
  if (SWZ) {
    int gx = gridDim.x;
    int nwg = gx * gridDim.y;
    int lin = by*gx + bx;
    int q = nwg >> 3, r = nwg & 7;
    int xcd = lin & 7, idx = lin >> 3;
    int swz = (xcd < r) ? (xcd*(q+1) + idx) : (r*(q+1) + (xcd-r)*q + idx);
    bx = swz % gx; by = swz / gx;
  }

  const unsigned short* Ab = A + (size_t)n*saN + (size_t)h*saH + (size_t)by*BM*lda;
  const unsigned short* Bb = B + (size_t)n*sbN + (size_t)h*sbH + (size_t)bx*BN*ldb;

  const unsigned short* aSrc[AISS]; int aOff[AISS];
#pragma unroll
  for (int r = 0; r < AISS; ++r) {
    int chunk = wid*AISS + r;
    int row = chunk*RPC + lane/CH;
    int col = ((lane % CH) ^ ((row >> SSH) & SW)) * 8;
    aSrc[r] = Ab + (size_t)row*lda + col;
    aOff[r] = chunk*512;
  }
  const unsigned short* bSrc[BISS]; int bOff[BISS];
#pragma unroll
  for (int r = 0; r < BISS; ++r) {
    int chunk = wid*BISS + r;
    int row = chunk*RPC + lane/CH;
    int col = ((lane % CH) ^ ((row >> SSH) & SW)) * 8;
    bSrc[r] = Bb + (size_t)row*ldb + col;
    bOff[r] = chunk*512;
  }

  v4f acc[MI][NI];
#pragma unroll
  for (int i = 0; i < MI; ++i)
#pragma unroll
    for (int j = 0; j < NI; ++j) acc[i][j] = (v4f){0.f,0.f,0.f,0.f};

  auto issue = [&](int tt, int buf) {
    int k0 = tt * BK;
#pragma unroll
    for (int r = 0; r < AISS; ++r) gload16(aSrc[r] + k0, &As[buf*TA + aOff[r]]);
#pragma unroll
    for (int r = 0; r < BISS; ++r) gload16(bSrc[r] + k0, &Bs[buf*TB + bOff[r]]);
  };

  int nt = K / BK;
  for (int p = 0; p < DEPTH-1 && p < nt; ++p) issue(p, p);
  int cbuf = 0;
  int ibuf = (DEPTH-1) % DEPTH;
  for (int tt = 0; tt < nt; ++tt) {
    int ahead = tt + DEPTH - 1;
    if (ahead < nt) {
      issue(ahead, ibuf);
      waitvm((DEPTH-1)*LPT);
    } else {
      waitvm((nt-1-tt)*LPT);
    }
    __builtin_amdgcn_s_barrier();
    asm volatile("" ::: "memory");
#pragma unroll
    for (int ks = 0; ks < BK/32; ++ks) {
      v8bf af[MI], bfr[NI];
#pragma unroll
      for (int i = 0; i < MI; ++i) {
        int row = wr*(BM/2) + i*16 + (lane & 15);
        int c = (ks*4 + (lane >> 4)) ^ ((row >> SSH) & SW);
        af[i] = *(const v8bf*)&As[cbuf*TA + row*BK + c*8];
      }
#pragma unroll
      for (int j = 0; j < NI; ++j) {
        int row = wc*(BN/2) + j*16 + (lane & 15);
        int c = (ks*4 + (lane >> 4)) ^ ((row >> SSH) & SW);
        bfr[j] = *(const v8bf*)&Bs[cbuf*TB + row*BK + c*8];
      }
#pragma unroll
      for (int i = 0; i < MI; ++i)
#pragma unroll
        for (int j = 0; j < NI; ++j)
          acc[i][j] = __builtin_amdgcn_mfma_f32_16x16x32_bf16(af[i], bfr[j], acc[i][j], 0, 0, 0);
    }
    asm volatile("s_waitcnt lgkmcnt(0)" ::: "memory");
    __builtin_amdgcn_s_barrier();
    asm volatile("" ::: "memory");
    cbuf = (cbuf + 1 == DEPTH) ? 0 : cbuf + 1;
    ibuf = (ibuf + 1 == DEPTH) ? 0 : ibuf + 1;
  }

  float* Cf = (float*)Cout;
  unsigned short* Ch = (unsigned short*)Cout;
  size_t cb = (size_t)n*scN + (size_t)h*scH;
  int grow0 = by*BM + wr*(BM/2);
  int gcol0 = bx*BN + wc*(BN/2);
#pragma unroll
  for (int i = 0; i < MI; ++i) {
#pragma unroll
    for (int j = 0; j < NI; ++j) {
      int col = gcol0 + j*16 + (lane & 15);
      float bval = 0.f;
      if (MODE == MODE_F32_BIAS || MODE == MODE_BF16_BIAS || MODE == MODE_BF16_BIAS_RELU)
        bval = bias[col];
#pragma unroll
      for (int r = 0; r < 4; ++r) {
        int row = grow0 + i*16 + (lane>>4)*4 + r;
        float v = acc[i][j][r];
        if (MODE == MODE_F32_BIAS) {
          Cf[cb + (size_t)row*ldc + col] = v + bval;
        } else if (MODE == MODE_F32_NOBIAS) {
          Cf[cb + (size_t)row*ldc + col] = v;
        } else if (MODE == MODE_PV) {
          Ch[cb + (size_t)row*ldc + col] = bf16b(v);
        } else {
          v += bval;
          if (MODE == MODE_BF16_BIAS_RELU) v = fmaxf(v, 0.f);
          Ch[cb + (size_t)row*ldc + col] = bf16b(v);
        }
      }
    }
  }
}

// ================= 256x256 / 8-wave / BK64 dbuf-counted GEMM =================
template<int MODE>
__global__ __launch_bounds__(512) void k_mm256(
    const unsigned short* __restrict__ A, int lda,
    const unsigned short* __restrict__ B, int ldb,
    void* __restrict__ Cout, int ldc,
    const float* __restrict__ bias, int K) {
  extern __shared__ __align__(16) unsigned short smem[];
  unsigned short* As = smem;
  unsigned short* Bs = smem + 2*16384;
  constexpr int TA = 256*64;
  int t = threadIdx.x, lane = t & 63, wid = t >> 6;
  int wr = wid >> 2, wc = wid & 3;

  int bx = blockIdx.x, by = blockIdx.y;
  {
    int gx = gridDim.x, nwg = gx * gridDim.y;
    int lin = by*gx + bx;
    int q = nwg >> 3, r = nwg & 7;
    int xcd = lin & 7, idx = lin >> 3;
    int swz = (xcd < r) ? (xcd*(q+1) + idx) : (r*(q+1) + (xcd-r)*q + idx);
    bx = swz % gx; by = swz / gx;
  }

  const unsigned short* Ab = A + (size_t)by*256*lda;
  const unsigned short* Bb = B + (size_t)bx*256*ldb;

  const unsigned short* aSrc[4]; int aOff[4];
  const unsigned short* bSrc[4]; int bOff[4];
#pragma unroll
  for (int r = 0; r < 4; ++r) {
    int chunk = wid*4 + r;
    int row = chunk*8 + (lane >> 3);
    int col = ((lane & 7) ^ (row & 7)) * 8;
    aSrc[r] = Ab + (size_t)row*lda + col;
    bSrc[r] = Bb + (size_t)row*ldb + col;
    aOff[r] = chunk*512;
    bOff[r] = chunk*512;
  }

  v4f acc[8][4];
#pragma unroll
  for (int i = 0; i < 8; ++i)
#pragma unroll
    for (int j = 0; j < 4; ++j) acc[i][j] = (v4f){0.f,0.f,0.f,0.f};

  auto issue = [&](int tt, int buf) {
    int k0 = tt << 6;
#pragma unroll
    for (int r = 0; r < 4; ++r) gload16(aSrc[r] + k0, &As[buf*TA + aOff[r]]);
#pragma unroll
    for (int r = 0; r < 4; ++r) gload16(bSrc[r] + k0, &Bs[buf*TA + bOff[r]]);
  };

  int nt = K >> 6;
  issue(0, 0);
  int cur = 0;
  for (int tt = 0; tt < nt; ++tt) {
    if (tt + 1 < nt) {
      issue(tt+1, cur^1);
      waitvm(8);
    } else {
      waitvm(0);
    }
    __builtin_amdgcn_s_barrier();
    asm volatile("" ::: "memory");
    __builtin_amdgcn_s_setprio(1);
#pragma unroll
    for (int ks = 0; ks < 2; ++ks) {
      v8bf af[8], bfr[4];
#pragma unroll
      for (int i = 0; i < 8; ++i) {
        int row = wr*128 + i*16 + (lane & 15);
        int c = (ks*4 + (lane >> 4)) ^ (row & 7);
        af[i] = *(const v8bf*)&As[cur*TA + row*64 + c*8];
      }
#pragma unroll
      for (int j = 0; j < 4; ++j) {
        int row = wc*64 + j*16 + (lane & 15);
        int c = (ks*4 + (lane >> 4)) ^ (row & 7);
        bfr[j] = *(const v8bf*)&Bs[cur*TA + row*64 + c*8];
      }
#pragma unroll
      for (int i = 0; i < 8; ++i)
#pragma unroll
        for (int j = 0; j < 4; ++j)
          acc[i][j] = __builtin_amdgcn_mfma_f32_16x16x32_bf16(af[i], bfr[j], acc[i][j], 0, 0, 0);
    }
    __builtin_amdgcn_s_setprio(0);
    asm volatile("s_waitcnt lgkmcnt(0)" ::: "memory");
    __builtin_amdgcn_s_barrier();
    asm volatile("" ::: "memory");
    cur ^= 1;
  }

  float* Cf = (float*)Cout;
  unsigned short* Ch = (unsigned short*)Cout;
  int grow0 = by*256 + wr*128;
  int gcol0 = bx*256 + wc*64;
#pragma unroll
  for (int i = 0; i < 8; ++i) {
#pragma unroll
    for (int j = 0; j < 4; ++j) {
      int col = gcol0 + j*16 + (lane & 15);
      float bval = 0.f;
      if (MODE == MODE_F32_BIAS || MODE == MODE_BF16_BIAS || MODE == MODE_BF16_BIAS_RELU)
        bval = bias[col];
#pragma unroll
      for (int r = 0; r < 4; ++r) {
        int row = grow0 + i*16 + (lane>>4)*4 + r;
        float v = acc[i][j][r];
        if (MODE == MODE_F32_BIAS) {
          Cf[(size_t)row*ldc + col] = v + bval;
        } else if (MODE == MODE_F32_NOBIAS) {
          Cf[(size_t)row*ldc + col] = v;
        } else {
          v += bval;
          if (MODE == MODE_BF16_BIAS_RELU) v = fmaxf(v, 0.f);
          Ch[(size_t)row*ldc + col] = bf16b(v);
        }
      }
    }
  }
}

// ====== fused attention: QK^T + scale + bias + softmax + PV, one block = 64 q-rows ======
// grid (4, 192). LDS: Qs 8K + Ks 32K + Vs 32K + Ps 32K = 104KB (1 block/CU).
// Each wave owns 16 q-rows; P stays wave-local (write+read own LDS rows, no barrier).
__global__ __launch_bounds__(256) void k_attn(
    const unsigned short* __restrict__ qkv,
    const unsigned short* __restrict__ vT,
    const unsigned short* __restrict__ biasb,
    unsigned short* __restrict__ O) {
  __shared__ unsigned short Qs[64*64];
  __shared__ unsigned short Ks[256*64];
  __shared__ unsigned short Vs[64*256];   // rows = d (64), cols = k (256), swizzled
  __shared__ unsigned short Ps[64*256];   // rows = q (64), cols = k (256), swizzled
  int t = threadIdx.x, lane = t & 63, wid = t >> 6;
  int z = blockIdx.y, n = z / NH, h = z - n*NH;
  int m0 = blockIdx.x * 64;
  const unsigned short* Qb = qkv + (size_t)n*SEQ*QKVN + (size_t)h*DKH + (size_t)m0*QKVN;
  const unsigned short* Kb = qkv + (size_t)n*SEQ*QKVN + H + (size_t)h*DKH;
  const unsigned short* Vb = vT + (size_t)z*DKH*SEQ;
#pragma unroll
  for (int r = 0; r < 2; ++r) {
    int chunk = wid*2 + r;
    int row = chunk*8 + (lane >> 3);
    int col = ((lane & 7) ^ (row & 7)) * 8;
    gload16(Qb + (size_t)row*QKVN + col, &Qs[chunk*512]);
  }
#pragma unroll
  for (int r = 0; r < 8; ++r) {
    int chunk = wid*8 + r;
    int row = chunk*8 + (lane >> 3);
    int col = ((lane & 7) ^ (row & 7)) * 8;
    gload16(Kb + (size_t)row*QKVN + col, &Ks[chunk*512]);
  }
#pragma unroll
  for (int r = 0; r < 8; ++r) {
    int chunk = wid*8 + r;              // 32 chunks, 2 rows each
    int row = chunk*2 + (lane >> 5);
    int cc = lane & 31;
    gload16(Vb + (size_t)row*SEQ + (size_t)((cc ^ (row & 7))*8), &Vs[chunk*512]);
  }
  __syncthreads();

  // ---- QK^T: wave's 16 q-rows x all 256 k-cols ----
  v4f acc[16];
#pragma unroll
  for (int j = 0; j < 16; ++j) acc[j] = (v4f){0.f,0.f,0.f,0.f};
#pragma unroll
  for (int ks = 0; ks < 2; ++ks) {
    int arow = wid*16 + (lane & 15);
    int ac = (ks*4 + (lane >> 4)) ^ (arow & 7);
    v8bf af = *(const v8bf*)&Qs[arow*64 + ac*8];
#pragma unroll
    for (int j = 0; j < 16; ++j) {
      int brow = j*16 + (lane & 15);
      int bc = (ks*4 + (lane >> 4)) ^ (brow & 7);
      v8bf bf = *(const v8bf*)&Ks[brow*64 + bc*8];
      acc[j] = __builtin_amdgcn_mfma_f32_16x16x32_bf16(af, bf, acc[j], 0, 0, 0);
    }
  }

  // ---- scale + bias + row softmax (16-lane groups) ----
  int col = lane & 15, quad = lane >> 4;
  const unsigned short* bb = biasb + (size_t)n*65536;
  float e[16][4];
  float rm[4] = {-1e30f, -1e30f, -1e30f, -1e30f};
#pragma unroll
  for (int r = 0; r < 4; ++r) {
    int row = m0 + wid*16 + quad*4 + r;
#pragma unroll
    for (int j = 0; j < 16; ++j) {
      float v = acc[j][r]*0.125f + b2f(bb[(size_t)row*256 + j*16 + col]);
      e[j][r] = v;
      rm[r] = fmaxf(rm[r], v);
    }
  }
#pragma unroll
  for (int r = 0; r < 4; ++r)
#pragma unroll
    for (int m = 1; m < 16; m <<= 1) rm[r] = fmaxf(rm[r], __shfl_xor(rm[r], m, 64));
  float rs[4] = {0.f, 0.f, 0.f, 0.f};
#pragma unroll
  for (int r = 0; r < 4; ++r)
#pragma unroll
    for (int j = 0; j < 16; ++j) {
      float ev = __expf(e[j][r] - rm[r]);
      e[j][r] = ev;
      rs[r] += ev;
    }
#pragma unroll
  for (int r = 0; r < 4; ++r) {
#pragma unroll
    for (int m = 1; m < 16; m <<= 1) rs[r] += __shfl_xor(rs[r], m, 64);
    rs[r] = 1.0f/rs[r];
  }

  // ---- P -> LDS (own 16 rows, involutive chunk swizzle) ----
#pragma unroll
  for (int r = 0; r < 4; ++r) {
    int row = wid*16 + quad*4 + r;      // local row
#pragma unroll
    for (int j = 0; j < 16; ++j) {
      int cc = j*2 + (col >> 3);
      Ps[row*256 + ((cc ^ (row & 7))*8) + (col & 7)] = bf16b(e[j][r]*rs[r]);
    }
  }
  asm volatile("s_waitcnt lgkmcnt(0)" ::: "memory");
  __builtin_amdgcn_sched_barrier(0);    // rule 18: don't let reads hoist above the wait

  // ---- PV: O[16 rows][64 d-cols], K=256 ----
  v4f po[4];
#pragma unroll
  for (int j = 0; j < 4; ++j) po[j] = (v4f){0.f,0.f,0.f,0.f};
#pragma unroll
  for (int kk = 0; kk < 8; ++kk) {      // K-step 32
    int arow = wid*16 + (lane & 15);
    int c = kk*4 + (lane >> 4);
    v8bf af = *(const v8bf*)&Ps[arow*256 + ((c ^ (arow & 7))*8)];
#pragma unroll
    for (int j = 0; j < 4; ++j) {
      int brow = j*16 + (lane & 15);
      v8bf bf = *(const v8bf*)&Vs[brow*256 + ((c ^ (brow & 7))*8)];
      po[j] = __builtin_amdgcn_mfma_f32_16x16x32_bf16(af, bf, po[j], 0, 0, 0);
    }
  }

  unsigned short* Ob = O + ((size_t)n*SEQ + m0)*H + (size_t)h*DKH;
#pragma unroll
  for (int j = 0; j < 4; ++j) {
    int ocol = j*16 + (lane & 15);
#pragma unroll
    for (int r = 0; r < 4; ++r) {
      int orow = wid*16 + quad*4 + r;
      Ob[(size_t)orow*H + ocol] = bf16b(po[j][r]);
    }
  }
}

// ============ weight transpose+cast ============
__global__ __launch_bounds__(256) void k_wT(const float* __restrict__ in,
                                            unsigned short* __restrict__ out,
                                            int Nn, int Kk) {
  int n0 = blockIdx.x*64, k0 = blockIdx.y*64;
  __shared__ float T[64][72];
  int t = threadIdx.x;
  int r = t >> 4, c4 = (t & 15) * 4;
#pragma unroll
  for (int i = 0; i < 4; ++i) {
    float4 v = *(const float4*)(in + (size_t)(k0 + r + i*16)*Nn + n0 + c4);
    T[c4+0][r+i*16] = v.x; T[c4+1][r+i*16] = v.y;
    T[c4+2][r+i*16] = v.z; T[c4+3][r+i*16] = v.w;
  }
  __syncthreads();
  int c = t >> 3, r8 = (t & 7) * 8;
#pragma unroll
  for (int i = 0; i < 2; ++i) {
    int cc = c + i*32;
    v8s o;
#pragma unroll
    for (int j = 0; j < 8; ++j) o[j] = (short)bf16b(T[cc][r8+j]);
    *(v8s*)(out + (size_t)(n0+cc)*Kk + k0 + r8) = o;
  }
}

__global__ void k_bqkv(const float* __restrict__ bq, const float* __restrict__ bk,
                       const float* __restrict__ bv, float* __restrict__ o) {
  int i = blockIdx.x*256 + threadIdx.x;
  if (i >= 3*QKVN) return;
  int l = i / QKVN, j = i - l*QKVN;
  float v = (j < H) ? bq[l*H + j] : (j < 2*H) ? bk[l*H + j - H] : bv[l*H + j - 2*H];
  o[i] = v;
}

__global__ __launch_bounds__(256) void k_cast(const float* __restrict__ x,
                                              float* __restrict__ enc,
                                              unsigned short* __restrict__ enc16) {
  size_t i = ((size_t)blockIdx.x*256 + threadIdx.x)*4;
  float4 v = *(const float4*)(x + i);
  *(float4*)(enc + i) = v;
  ushort4 u = { bf16b(v.x), bf16b(v.y), bf16b(v.z), bf16b(v.w) };
  *(ushort4*)(enc16 + i) = u;
}

__global__ __launch_bounds__(256) void k_vT(const unsigned short* __restrict__ qkv,
                                            unsigned short* __restrict__ vT) {
  int z = blockIdx.x, n = z/NH, h = z - n*NH;
  const unsigned short* src = qkv + (size_t)n*SEQ*QKVN + 2*H + (size_t)h*DKH;
  __shared__ unsigned short tile[64][264];
  int t = threadIdx.x;
  int r0 = t >> 3, d0 = (t & 7) * 8;
#pragma unroll
  for (int i = 0; i < 8; ++i) {
    int r = r0 + i*32;
    v8s vv = *(const v8s*)(src + (size_t)r*QKVN + d0);
#pragma unroll
    for (int j = 0; j < 8; ++j) tile[d0+j][r] = (unsigned short)vv[j];
  }
  __syncthreads();
  int d = t >> 2, rb = (t & 3) * 64;
  unsigned short* dst = vT + (size_t)z*DKH*SEQ + (size_t)d*SEQ + rb;
#pragma unroll
  for (int i = 0; i < 8; ++i)
    *(v8s*)(dst + i*8) = *(const v8s*)&tile[d][rb + i*8];
}

__global__ __launch_bounds__(256) void k_fusion_weights(
    const float* __restrict__ x, const float* __restrict__ lin_w,
    const float* __restrict__ lin_b, float* __restrict__ wsoft) {
  int n = blockIdx.x, t = threadIdx.x;
  __shared__ float xm[H];
  __shared__ float sred[4];
  __shared__ float logits[12];
  if (t < 192) {
    const float4* p = (const float4*)(x + (size_t)n*SEQ*H) + t;
    float4 s = {0.f,0.f,0.f,0.f};
    for (int r = 0; r < SEQ; ++r) {
      float4 v = p[(size_t)r*192];
      s.x += v.x; s.y += v.y; s.z += v.z; s.w += v.w;
    }
    xm[t*4+0] = s.x*(1.0f/SEQ); xm[t*4+1] = s.y*(1.0f/SEQ);
    xm[t*4+2] = s.z*(1.0f/SEQ); xm[t*4+3] = s.w*(1.0f/SEQ);
  }
  __syncthreads();
  float lacc[12];
#pragma unroll
  for (int j = 0; j < 12; ++j) lacc[j] = 0.f;
  for (int hh = t; hh < H; hh += 256) {
    float xv = xm[hh];
#pragma unroll
    for (int j = 0; j < 12; ++j) lacc[j] += xv * lin_w[hh*12 + j];
  }
  for (int j = 0; j < 12; ++j) {
    float v = lacc[j];
#pragma unroll
    for (int m = 1; m < 64; m <<= 1) v += __shfl_xor(v, m, 64);
    if ((t & 63) == 0) sred[t >> 6] = v;
    __syncthreads();
    if (t == 0) logits[j] = sred[0]+sred[1]+sred[2]+sred[3] + lin_b[j];
    __syncthreads();
  }
  if (t < 3) {
    int l = t;
    float mx = -1e30f;
    for (int m = 0; m < 4; ++m) mx = fmaxf(mx, logits[l*4+m]);
    float e[4], s = 0.f;
    for (int m = 0; m < 4; ++m) { e[m] = expf(logits[l*4+m]-mx); s += e[m]; }
    for (int m = 0; m < 4; ++m) wsoft[(l*NSEQ + n)*4 + m] = e[m]/s;
  }
}

// mask fusion -> bf16 bias
__global__ __launch_bounds__(256) void k_bias(
    const float* __restrict__ cm, const float* __restrict__ dm,
    const float* __restrict__ ent, const float* __restrict__ sm,
    const float* __restrict__ wsoft, int l, unsigned short* __restrict__ bias) {
  int g = blockIdx.x*256 + threadIdx.x;
  int n = g >> 14;
  int k4 = g & 63;
  const float* w = wsoft + (l*NSEQ + n)*4;
  float w0 = w[0], w1 = w[1], w2 = w[2], w3 = w[3];
  float4 c = ((const float4*)cm)[g];
  float4 d = ((const float4*)dm)[g];
  float4 s = ((const float4*)sm)[g];
  float4 e = ((const float4*)(ent + (size_t)n*SEQ))[k4];
  ushort4 o;
  o.x = bf16b(w0*c.x + w1*d.x + w2*e.x + w3*s.x);
  o.y = bf16b(w0*c.y + w1*d.y + w2*e.y + w3*s.y);
  o.z = bf16b(w0*c.z + w1*d.z + w2*e.z + w3*s.z);
  o.w = bf16b(w0*c.w + w1*d.w + w2*e.w + w3*s.w);
  ((ushort4*)bias)[g] = o;
}

__global__ void k_nonpad(const int* __restrict__ ids, float* __restrict__ npad) {
  int i = blockIdx.x*256 + threadIdx.x;
  if (i < MROWS) npad[i] = (ids[i] != 1) ? 1.0f : 0.0f;
}

__global__ __launch_bounds__(256) void k_ln(
    const float* __restrict__ f, float* __restrict__ enc,
    unsigned short* __restrict__ enc16,
    const float* __restrict__ g, const float* __restrict__ b,
    const float* __restrict__ npad) {
  int r = blockIdx.x, t = threadIdx.x;
  size_t base = (size_t)r*H;
  float v0 = f[base+t]     + enc[base+t];
  float v1 = f[base+t+256] + enc[base+t+256];
  float v2 = f[base+t+512] + enc[base+t+512];
  __shared__ float sred[4];
  float s = v0+v1+v2;
#pragma unroll
  for (int m = 1; m < 64; m <<= 1) s += __shfl_xor(s, m, 64);
  if ((t & 63) == 0) sred[t >> 6] = s;
  __syncthreads();
  float mean = (sred[0]+sred[1]+sred[2]+sred[3]) * (1.0f/H);
  __syncthreads();
  float d0 = v0-mean, d1 = v1-mean, d2 = v2-mean;
  float ss = d0*d0 + d1*d1 + d2*d2;
#pragma unroll
  for (int m = 1; m < 64; m <<= 1) ss += __shfl_xor(ss, m, 64);
  if ((t & 63) == 0) sred[t >> 6] = ss;
  __syncthreads();
  float var = (sred[0]+sred[1]+sred[2]+sred[3]) * (1.0f/H);
  float rstd = 1.0f/sqrtf(var + 1e-5f);
  float npv = npad[r];
  float o0 = (g[t]    *d0*rstd + b[t]    )*npv;
  float o1 = (g[t+256]*d1*rstd + b[t+256])*npv;
  float o2 = (g[t+512]*d2*rstd + b[t+512])*npv;
  enc[base+t]     = o0; enc[base+t+256] = o1; enc[base+t+512] = o2;
  enc16[base+t]     = bf16b(o0);
  enc16[base+t+256] = bf16b(o1);
  enc16[base+t+512] = bf16b(o2);
}

__global__ __launch_bounds__(256) void k_ln4(
    const float* __restrict__ p, float* __restrict__ enc,
    unsigned short* __restrict__ enc16,
    const float* __restrict__ g, const float* __restrict__ b,
    const float* __restrict__ npad, const float* __restrict__ cbias) {
  int r = blockIdx.x, t = threadIdx.x;
  size_t base = (size_t)r*H;
  const size_t PS = (size_t)MROWS*H;
  float v0 = p[base+t]     + p[PS+base+t]     + p[2*PS+base+t]     + p[3*PS+base+t]     + cbias[t]     + enc[base+t];
  float v1 = p[base+t+256] + p[PS+base+t+256] + p[2*PS+base+t+256] + p[3*PS+base+t+256] + cbias[t+256] + enc[base+t+256];
  float v2 = p[base+t+512] + p[PS+base+t+512] + p[2*PS+base+t+512] + p[3*PS+base+t+512] + cbias[t+512] + enc[base+t+512];
  __shared__ float sred[4];
  float s = v0+v1+v2;
#pragma unroll
  for (int m = 1; m < 64; m <<= 1) s += __shfl_xor(s, m, 64);
  if ((t & 63) == 0) sred[t >> 6] = s;
  __syncthreads();
  float mean = (sred[0]+sred[1]+sred[2]+sred[3]) * (1.0f/H);
  __syncthreads();
  float d0 = v0-mean, d1 = v1-mean, d2 = v2-mean;
  float ss = d0*d0 + d1*d1 + d2*d2;
#pragma unroll
  for (int m = 1; m < 64; m <<= 1) ss += __shfl_xor(ss, m, 64);
  if ((t & 63) == 0) sred[t >> 6] = ss;
  __syncthreads();
  float var = (sred[0]+sred[1]+sred[2]+sred[3]) * (1.0f/H);
  float rstd = 1.0f/sqrtf(var + 1e-5f);
  float npv = npad[r];
  float o0 = (g[t]    *d0*rstd + b[t]    )*npv;
  float o1 = (g[t+256]*d1*rstd + b[t+256])*npv;
  float o2 = (g[t+512]*d2*rstd + b[t+512])*npv;
  enc[base+t]     = o0; enc[base+t+256] = o1; enc[base+t+512] = o2;
  enc16[base+t]     = bf16b(o0);
  enc16[base+t+256] = bf16b(o1);
  enc16[base+t+512] = bf16b(o2);
}

__global__ __launch_bounds__(256) void k_colstats(
    const float* __restrict__ enc, float* __restrict__ csum, float* __restrict__ csq) {
  int r0 = blockIdx.x*16, t = threadIdx.x;
  float s0=0,s1=0,s2=0,q0=0,q1=0,q2=0;
  for (int r = 0; r < 16; ++r) {
    const float* row = enc + (size_t)(r0+r)*H;
    float a = row[t], b = row[t+256], c = row[t+512];
    s0 += a; s1 += b; s2 += c;
    q0 += a*a; q1 += b*b; q2 += c*c;
  }
  atomicAdd(&csum[t],     s0); atomicAdd(&csum[t+256], s1); atomicAdd(&csum[t+512], s2);
  atomicAdd(&csq[t],      q0); atomicAdd(&csq[t+256],  q1); atomicAdd(&csq[t+512],  q2);
}

__global__ __launch_bounds__(256) void k_poolprep(
    const float* __restrict__ x, const float* __restrict__ enc,
    const float* __restrict__ csum, const float* __restrict__ csq,
    const float* __restrict__ bnt_g, const float* __restrict__ bnt_b,
    float* __restrict__ ps0) {
  int n = blockIdx.x, t = threadIdx.x;
  for (int hh = t; hh < H; hh += 256) {
    float m = csum[hh] * (1.0f/MROWS);
    float var = csq[hh] * (1.0f/MROWS) - m*m;
    float rstd = 1.0f/sqrtf(var + 1e-5f);
    float e = enc[(size_t)n*SEQ*H + hh];
    ps0[n*H + hh] = x[(size_t)n*SEQ*H + hh] + bnt_g[hh]*(e-m)*rstd + bnt_b[hh];
  }
}

__global__ __launch_bounds__(256) void k_poolmm(
    const float* __restrict__ ps0, const float* __restrict__ pool_w,
    const float* __restrict__ pool_b, float* __restrict__ pooled) {
  int n = blockIdx.y, jb = blockIdx.x*64;
  __shared__ float s0[H];
  __shared__ float part[4][64];
  int t = threadIdx.x;
  for (int hh = t; hh < H; hh += 256) s0[hh] = ps0[n*H + hh];
  __syncthreads();
  int j = t & 63, q = t >> 6;
  float a = 0.f;
  int h0 = q*192;
  for (int hh = h0; hh < h0+192; ++hh)
    a = fmaf(s0[hh], pool_w[(size_t)hh*H + jb + j], a);
  part[q][j] = a;
  __syncthreads();
  if (t < 64) {
    float v = part[0][t]+part[1][t]+part[2][t]+part[3][t] + pool_b[jb+t];
    pooled[n*H + jb + t] = tanhf(v);
  }
}

__global__ __launch_bounds__(256) void k_final(
    const float* __restrict__ pooled, const float* __restrict__ bn_g,
    const float* __restrict__ bn_b, const float* __restrict__ cls_w,
    const float* __restrict__ cls_b, float* __restrict__ out) {
  int t = threadIdx.x;
  float acc[16];
#pragma unroll
  for (int n = 0; n < 16; ++n) acc[n] = 0.f;
  for (int hh = t; hh < H; hh += 256) {
    float p[16]; float m = 0.f;
#pragma unroll
    for (int n = 0; n < 16; ++n) { p[n] = pooled[n*H + hh]; m += p[n]; }
    m *= (1.0f/16.f);
    float var = 0.f;
#pragma unroll
    for (int n = 0; n < 16; ++n) { float d = p[n]-m; var += d*d; }
    var *= (1.0f/16.f);
    float rstd = 1.0f/sqrtf(var + 1e-5f);
    float gw = bn_g[hh]*rstd*cls_w[hh];
    float off = bn_b[hh]*cls_w[hh];
#pragma unroll
    for (int n = 0; n < 16; ++n) acc[n] += (p[n]-m)*gw + off;
  }
  __shared__ float sred[4];
  for (int n = 0; n < 16; ++n) {
    float v = acc[n];
#pragma unroll
    for (int m = 1; m < 64; m <<= 1) v += __shfl_xor(v, m, 64);
    if ((t & 63) == 0) sred[t >> 6] = v;
    __syncthreads();
    if (t == 0) out[n] = sred[0]+sred[1]+sred[2]+sred[3] + cls_b[0];
    __syncthreads();
  }
}

extern "C" void kernel_launch(void* const* d_in, const int* in_sizes, int n_in,
                              void* d_out, int out_size, void* d_ws, size_t ws_size,
                              hipStream_t stream) {
  const int*   input_ids = (const int*)  d_in[0];
  const float* x       = (const float*)d_in[1];
  const float* cm      = (const float*)d_in[3];
  const float* dm      = (const float*)d_in[4];
  const float* ent     = (const float*)d_in[5];
  const float* sm      = (const float*)d_in[6];
  const float* lin_w   = (const float*)d_in[7];
  const float* lin_b   = (const float*)d_in[8];
  const float* Wq      = (const float*)d_in[9];
  const float* bq      = (const float*)d_in[10];
  const float* Wk      = (const float*)d_in[11];
  const float* bk      = (const float*)d_in[12];
  const float* Wv      = (const float*)d_in[13];
  const float* bv      = (const float*)d_in[14];
  const float* Wo      = (const float*)d_in[15];
  const float* bo      = (const float*)d_in[16];
  const float* ln1_g   = (const float*)d_in[17];
  const float* ln1_b   = (const float*)d_in[18];
  const float* W1      = (const float*)d_in[19];
  const float* b1      = (const float*)d_in[20];
  const float* W2      = (const float*)d_in[21];
  const float* b2      = (const float*)d_in[22];
  const float* ln2_g   = (const float*)d_in[23];
  const float* ln2_b   = (const float*)d_in[24];
  const float* bnt_g   = (const float*)d_in[25];
  const float* bnt_b   = (const float*)d_in[26];
  const float* pool_w  = (const float*)d_in[27];
  const float* pool_b  = (const float*)d_in[28];
  const float* bn_g    = (const float*)d_in[29];
  const float* bn_b    = (const float*)d_in[30];
  const float* cls_w   = (const float*)d_in[31];
  const float* cls_b   = (const float*)d_in[32];
  float* out = (float*)d_out;
  (void)ws_size; (void)n_in; (void)in_sizes; (void)out_size;

  char* wsb = (char*)d_ws;
  size_t off = 0;
  auto alloc = [&](size_t bytes) {
    void* p = (void*)(wsb + off);
    off += (bytes + 255) & ~(size_t)255;
    return p;
  };
  float* enc            = (float*)alloc((size_t)MROWS*H*4);
  unsigned short* enc16 = (unsigned short*)alloc((size_t)MROWS*H*2);
  unsigned short* qkv16 = (unsigned short*)alloc((size_t)MROWS*QKVN*2);
  unsigned short* vT    = (unsigned short*)alloc((size_t)192*DKH*SEQ*2);
  unsigned short* ob16  = (unsigned short*)alloc((size_t)MROWS*H*2);
  float* fbuf           = (float*)alloc((size_t)4*MROWS*H*4);
  unsigned short* PH    = (unsigned short*)alloc((size_t)MROWS*DI*2);
  unsigned short* hidden16 = PH;
  unsigned short* biasb = (unsigned short*)alloc((size_t)NSEQ*SEQ*SEQ*2);
  unsigned short* WqkvT = (unsigned short*)alloc((size_t)3*QKVN*H*2);
  unsigned short* WoT   = (unsigned short*)alloc((size_t)3*H*H*2);
  unsigned short* W1T   = (unsigned short*)alloc((size_t)3*DI*H*2);
  unsigned short* W2T   = (unsigned short*)alloc((size_t)3*H*DI*2);
  float* bqkv   = (float*)alloc(3*QKVN*4);
  float* wsoft  = (float*)alloc(3*16*4*4);
  float* npad   = (float*)alloc(MROWS*4);
  float* csum   = (float*)alloc(H*4);
  float* csq    = (float*)alloc(H*4);
  float* ps0    = (float*)alloc(16*H*4);
  float* pooled = (float*)alloc(16*H*4);

  k_cast<<<MROWS*H/1024, 256, 0, stream>>>(x, enc, enc16);
  k_fusion_weights<<<16, 256, 0, stream>>>(x, lin_w, lin_b, wsoft);
  k_nonpad<<<MROWS/256, 256, 0, stream>>>(input_ids, npad);
  k_bqkv<<<27, 256, 0, stream>>>(bq, bk, bv, bqkv);
  for (int l = 0; l < 3; ++l) {
    k_wT<<<dim3(12,12), 256, 0, stream>>>(Wq + (size_t)l*H*H, WqkvT + (size_t)l*QKVN*H,           H, H);
    k_wT<<<dim3(12,12), 256, 0, stream>>>(Wk + (size_t)l*H*H, WqkvT + (size_t)l*QKVN*H + H*H,     H, H);
    k_wT<<<dim3(12,12), 256, 0, stream>>>(Wv + (size_t)l*H*H, WqkvT + (size_t)l*QKVN*H + 2*H*H,   H, H);
    k_wT<<<dim3(12,12), 256, 0, stream>>>(Wo + (size_t)l*H*H, WoT + (size_t)l*H*H,                H, H);
    k_wT<<<dim3(64,12), 256, 0, stream>>>(W1 + (size_t)l*H*DI, W1T + (size_t)l*DI*H,              DI, H);
    k_wT<<<dim3(12,64), 256, 0, stream>>>(W2 + (size_t)l*DI*H, W2T + (size_t)l*H*DI,              H, DI);
  }

  for (int l = 0; l < 3; ++l) {
    k_bias<<<1024, 256, 0, stream>>>(cm, dm, ent, sm, wsoft, l, biasb);
    // QKV: 128x128, BK=32, depth-2 counted
    k_mm<128,128,MODE_BF16_BIAS,32,2,true><<<dim3(18,32,1), 256, 0, stream>>>(
        enc16, H, 0, 0, WqkvT + (size_t)l*QKVN*H, H, 0, 0,
        qkv16, QKVN, 0, 0, bqkv + l*QKVN, H, 1);
    k_vT<<<192, 256, 0, stream>>>(qkv16, vT);
    // fused attention: QK^T + bias + softmax + PV -> ob16
    k_attn<<<dim3(4,192), 256, 0, stream>>>(qkv16, vT, biasb, ob16);
    // Wo (64x64 BK=64 depth-3 + swizzle)  [R9-proven config]
    k_mm<64,64,MODE_F32_BIAS,64,3,true><<<dim3(12,64,1), 256, 0, stream>>>(
        ob16, H, 0, 0, WoT + (size_t)l*H*H, H, 0, 0,
        fbuf, H, 0, 0, bo + l*H, H, 1);
    k_ln<<<MROWS, 256, 0, stream>>>(fbuf, enc, enc16, ln1_g + l*H, ln1_b + l*H, npad);
    // W1 + ReLU: 256x256 8-wave dbuf-counted  [R9-proven config]
    k_mm256<MODE_BF16_BIAS_RELU><<<dim3(16,16), 512, 131072, stream>>>(
        enc16, H, W1T + (size_t)l*DI*H, H, hidden16, DI, b1 + l*DI, H);
    // W2: split-K4, 128x128, BK=32, depth-2 counted
    k_mm<128,128,MODE_F32_NOBIAS,32,2,true><<<dim3(6,32,4), 256, 0, stream>>>(
        hidden16, DI, 0, 1024, W2T + (size_t)l*H*DI, DI, 0, 1024,
        fbuf, H, 0, (long long)MROWS*H, nullptr, 1024, 4);
    k_ln4<<<MROWS, 256, 0, stream>>>(fbuf, enc, enc16, ln2_g + l*H, ln2_b + l*H, npad, b2 + l*H);
  }

  hipMemsetAsync(csum, 0, H*sizeof(float), stream);
  hipMemsetAsync(csq,  0, H*sizeof(float), stream);
  k_colstats<<<256, 256, 0, stream>>>(enc, csum, csq);
  k_poolprep<<<16, 256, 0, stream>>>(x, enc, csum, csq, bnt_g, bnt_b, ps0);
  k_poolmm<<<dim3(12,16), 256, 0, stream>>>(ps0, pool_w, pool_b, pooled);
  k_final<<<1, 256, 0, stream>>>(pooled, bn_g, bn_b, cls_w, cls_b, out);
}

// Round 12
// 638.149 us; speedup vs baseline: 1.0266x; 1.0077x over previous
//
#include <hip/hip_runtime.h>
#include <hip/hip_bf16.h>
#include <math.h>

#define NSEQ 16
#define SEQ 256
#define H 768
#define NH 12
#define DKH 64
#define DI 4096
#define MROWS (NSEQ*SEQ)   // 4096
#define QKVN (3*H)         // 2304

typedef __bf16 v8bf __attribute__((ext_vector_type(8)));
typedef float  v4f  __attribute__((ext_vector_type(4)));
typedef short  v8s  __attribute__((ext_vector_type(8)));

__device__ inline unsigned short bf16b(float f) {
  __hip_bfloat16 h = __float2bfloat16(f);
  return *reinterpret_cast<unsigned short*>(&h);
}
__device__ inline float b2f(unsigned short b) {
  return __uint_as_float(((unsigned int)b) << 16);
}

__device__ __forceinline__ void gload16(const void* g, void* l) {
  __builtin_amdgcn_global_load_lds((const __attribute__((address_space(1))) void*)g,
                                   (__attribute__((address_space(3))) void*)l, 16, 0, 0);
}

__device__ __forceinline__ void waitvm(int n) {
  switch (n) {
    case 0:  asm volatile("s_waitcnt vmcnt(0)" ::: "memory"); break;
    case 2:  asm volatile("s_waitcnt vmcnt(2)" ::: "memory"); break;
    case 4:  asm volatile("s_waitcnt vmcnt(4)" ::: "memory"); break;
    case 8:  asm volatile("s_waitcnt vmcnt(8)" ::: "memory"); break;
    case 12: asm volatile("s_waitcnt vmcnt(12)" ::: "memory"); break;
    case 16: asm volatile("s_waitcnt vmcnt(16)" ::: "memory"); break;
    default: asm volatile("s_waitcnt vmcnt(0)" ::: "memory"); break;
  }
}

enum { MODE_F32_BIAS=0, MODE_BF16_BIAS=1, MODE_BF16_BIAS_RELU=2, MODE_SCORES=3, MODE_PV=4, MODE_F32_NOBIAS=5 };

// ================= bf16 MFMA GEMM (4 waves), BK parameterized =================
template<int BM, int BN, int MODE, int BK, int DEPTH, bool SWZ>
__global__ __launch_bounds__(256) void k_mm(
    const unsigned short* __restrict__ A, int lda, long long saN, long long saH,
    const unsigned short* __restrict__ B, int ldb, long long sbN, long long sbH,
    void* __restrict__ Cout, int ldc, long long scN, long long scH,
    const float* __restrict__ bias, int K, int nhdiv) {
  constexpr int MI = BM/32, NI = BN/32;
  constexpr int CH  = BK/8;
  constexpr int RPC = 512/BK;
  constexpr int SW  = CH - 1;
  constexpr int SSH = (BK == 32) ? 1 : 0;
  constexpr int AISS = BM*BK/2048, BISS = BN*BK/2048;
  constexpr int LPT = AISS + BISS;
  constexpr int TA = BM*BK, TB = BN*BK;
  __shared__ unsigned short As[DEPTH*TA];
  __shared__ unsigned short Bs[DEPTH*TB];
  int t = threadIdx.x;
  int z = blockIdx.z, n = z / nhdiv, h = z - n*nhdiv;
  int lane = t & 63, wid = t >> 6, wr = wid >> 1, wc = wid & 1;

  int bx = blockIdx.x, by = blockIdx.y;
  if (SWZ) {
    int gx = gridDim.x;
    int nwg = gx * gridDim.y;
    int lin = by*gx + bx;
    int q = nwg >> 3, r = nwg & 7;
    int xcd = lin & 7, idx = lin >> 3;
    int swz = (xcd < r) ? (xcd*(q+1) + idx) : (r*(q+1) + (xcd-r)*q + idx);
    bx = swz % gx; by = swz / gx;
  }

  const unsigned short* Ab = A + (size_t)n*saN + (size_t)h*saH + (size_t)by*BM*lda;
  const unsigned short* Bb = B + (size_t)n*sbN + (size_t)h*sbH + (size_t)bx*BN*ldb;

  const unsigned short* aSrc[AISS]; int aOff[AISS];
#pragma unroll
  for (int r = 0; r < AISS; ++r) {
    int chunk = wid*AISS + r;
    int row = chunk*RPC + lane/CH;
    int col = ((lane % CH) ^ ((row >> SSH) & SW)) * 8;
    aSrc[r] = Ab + (size_t)row*lda + col;
    aOff[r] = chunk*512;
  }
  const unsigned short* bSrc[BISS]; int bOff[BISS];
#pragma unroll
  for (int r = 0; r < BISS; ++r) {
    int chunk = wid*BISS + r;
    int row = chunk*RPC + lane/CH;
    int col = ((lane % CH) ^ ((row >> SSH) & SW)) * 8;
    bSrc[r] = Bb + (size_t)row*ldb + col;
    bOff[r] = chunk*512;
  }

  v4f acc[MI][NI];
#pragma unroll
  for (int i = 0; i < MI; ++i)
#pragma unroll
    for (int j = 0; j < NI; ++j) acc[i][j] = (v4f){0.f,0.f,0.f,0.f};

  auto issue = [&](int tt, int buf) {
    int k0 = tt * BK;
#pragma unroll
    for (int r = 0; r < AISS; ++r) gload16(aSrc[r] + k0, &As[buf*TA + aOff[r]]);
#pragma unroll
    for (int r = 0; r < BISS; ++r) gload16(bSrc[r] + k0, &Bs[buf*TB + bOff[r]]);
  };

  int nt = K / BK;
  for (int p = 0; p < DEPTH-1 && p < nt; ++p) issue(p, p);
  int cbuf = 0;
  int ibuf = (DEPTH-1) % DEPTH;
  for (int tt = 0; tt < nt; ++tt) {
    int ahead = tt + DEPTH - 1;
    if (ahead < nt) {
      issue(ahead, ibuf);
      waitvm((DEPTH-1)*LPT);
    } else {
      waitvm((nt-1-tt)*LPT);
    }
    __builtin_amdgcn_s_barrier();
    asm volatile("" ::: "memory");
#pragma unroll
    for (int ks = 0; ks < BK/32; ++ks) {
      v8bf af[MI], bfr[NI];
#pragma unroll
      for (int i = 0; i < MI; ++i) {
        int row = wr*(BM/2) + i*16 + (lane & 15);
        int c = (ks*4 + (lane >> 4)) ^ ((row >> SSH) & SW);
        af[i] = *(const v8bf*)&As[cbuf*TA + row*BK + c*8];
      }
#pragma unroll
      for (int j = 0; j < NI; ++j) {
        int row = wc*(BN/2) + j*16 + (lane & 15);
        int c = (ks*4 + (lane >> 4)) ^ ((row >> SSH) & SW);
        bfr[j] = *(const v8bf*)&Bs[cbuf*TB + row*BK + c*8];
      }
#pragma unroll
      for (int i = 0; i < MI; ++i)
#pragma unroll
        for (int j = 0; j < NI; ++j)
          acc[i][j] = __builtin_amdgcn_mfma_f32_16x16x32_bf16(af[i], bfr[j], acc[i][j], 0, 0, 0);
    }
    asm volatile("s_waitcnt lgkmcnt(0)" ::: "memory");
    __builtin_amdgcn_s_barrier();
    asm volatile("" ::: "memory");
    cbuf = (cbuf + 1 == DEPTH) ? 0 : cbuf + 1;
    ibuf = (ibuf + 1 == DEPTH) ? 0 : ibuf + 1;
  }

  float* Cf = (float*)Cout;
  unsigned short* Ch = (unsigned short*)Cout;
  size_t cb = (size_t)n*scN + (size_t)h*scH;
  int grow0 = by*BM + wr*(BM/2);
  int gcol0 = bx*BN + wc*(BN/2);
#pragma unroll
  for (int i = 0; i < MI; ++i) {
#pragma unroll
    for (int j = 0; j < NI; ++j) {
      int col = gcol0 + j*16 + (lane & 15);
      float bval = 0.f;
      if (MODE == MODE_F32_BIAS || MODE == MODE_BF16_BIAS || MODE == MODE_BF16_BIAS_RELU)
        bval = bias[col];
#pragma unroll
      for (int r = 0; r < 4; ++r) {
        int row = grow0 + i*16 + (lane>>4)*4 + r;
        float v = acc[i][j][r];
        if (MODE == MODE_F32_BIAS) {
          Cf[cb + (size_t)row*ldc + col] = v + bval;
        } else if (MODE == MODE_F32_NOBIAS) {
          Cf[cb + (size_t)row*ldc + col] = v;
        } else if (MODE == MODE_PV) {
          Ch[cb + (size_t)row*ldc + col] = bf16b(v);
        } else {
          v += bval;
          if (MODE == MODE_BF16_BIAS_RELU) v = fmaxf(v, 0.f);
          Ch[cb + (size_t)row*ldc + col] = bf16b(v);
        }
      }
    }
  }
}

// ================= 256x256 / 8-wave / BK64 dbuf-counted GEMM =================
template<int MODE>
__global__ __launch_bounds__(512) void k_mm256(
    const unsigned short* __restrict__ A, int lda,
    const unsigned short* __restrict__ B, int ldb,
    void* __restrict__ Cout, int ldc,
    const float* __restrict__ bias, int K) {
  extern __shared__ __align__(16) unsigned short smem[];
  unsigned short* As = smem;
  unsigned short* Bs = smem + 2*16384;
  constexpr int TA = 256*64;
  int t = threadIdx.x, lane = t & 63, wid = t >> 6;
  int wr = wid >> 2, wc = wid & 3;

  int bx = blockIdx.x, by = blockIdx.y;
  {
    int gx = gridDim.x, nwg = gx * gridDim.y;
    int lin = by*gx + bx;
    int q = nwg >> 3, r = nwg & 7;
    int xcd = lin & 7, idx = lin >> 3;
    int swz = (xcd < r) ? (xcd*(q+1) + idx) : (r*(q+1) + (xcd-r)*q + idx);
    bx = swz % gx; by = swz / gx;
  }

  const unsigned short* Ab = A + (size_t)by*256*lda;
  const unsigned short* Bb = B + (size_t)bx*256*ldb;

  const unsigned short* aSrc[4]; int aOff[4];
  const unsigned short* bSrc[4]; int bOff[4];
#pragma unroll
  for (int r = 0; r < 4; ++r) {
    int chunk = wid*4 + r;
    int row = chunk*8 + (lane >> 3);
    int col = ((lane & 7) ^ (row & 7)) * 8;
    aSrc[r] = Ab + (size_t)row*lda + col;
    bSrc[r] = Bb + (size_t)row*ldb + col;
    aOff[r] = chunk*512;
    bOff[r] = chunk*512;
  }

  v4f acc[8][4];
#pragma unroll
  for (int i = 0; i < 8; ++i)
#pragma unroll
    for (int j = 0; j < 4; ++j) acc[i][j] = (v4f){0.f,0.f,0.f,0.f};

  auto issue = [&](int tt, int buf) {
    int k0 = tt << 6;
#pragma unroll
    for (int r = 0; r < 4; ++r) gload16(aSrc[r] + k0, &As[buf*TA + aOff[r]]);
#pragma unroll
    for (int r = 0; r < 4; ++r) gload16(bSrc[r] + k0, &Bs[buf*TA + bOff[r]]);
  };

  int nt = K >> 6;
  issue(0, 0);
  int cur = 0;
  for (int tt = 0; tt < nt; ++tt) {
    if (tt + 1 < nt) {
      issue(tt+1, cur^1);
      waitvm(8);
    } else {
      waitvm(0);
    }
    __builtin_amdgcn_s_barrier();
    asm volatile("" ::: "memory");
    __builtin_amdgcn_s_setprio(1);
#pragma unroll
    for (int ks = 0; ks < 2; ++ks) {
      v8bf af[8], bfr[4];
#pragma unroll
      for (int i = 0; i < 8; ++i) {
        int row = wr*128 + i*16 + (lane & 15);
        int c = (ks*4 + (lane >> 4)) ^ (row & 7);
        af[i] = *(const v8bf*)&As[cur*TA + row*64 + c*8];
      }
#pragma unroll
      for (int j = 0; j < 4; ++j) {
        int row = wc*64 + j*16 + (lane & 15);
        int c = (ks*4 + (lane >> 4)) ^ (row & 7);
        bfr[j] = *(const v8bf*)&Bs[cur*TA + row*64 + c*8];
      }
#pragma unroll
      for (int i = 0; i < 8; ++i)
#pragma unroll
        for (int j = 0; j < 4; ++j)
          acc[i][j] = __builtin_amdgcn_mfma_f32_16x16x32_bf16(af[i], bfr[j], acc[i][j], 0, 0, 0);
    }
    __builtin_amdgcn_s_setprio(0);
    asm volatile("s_waitcnt lgkmcnt(0)" ::: "memory");
    __builtin_amdgcn_s_barrier();
    asm volatile("" ::: "memory");
    cur ^= 1;
  }

  float* Cf = (float*)Cout;
  unsigned short* Ch = (unsigned short*)Cout;
  int grow0 = by*256 + wr*128;
  int gcol0 = bx*256 + wc*64;
#pragma unroll
  for (int i = 0; i < 8; ++i) {
#pragma unroll
    for (int j = 0; j < 4; ++j) {
      int col = gcol0 + j*16 + (lane & 15);
      float bval = 0.f;
      if (MODE == MODE_F32_BIAS || MODE == MODE_BF16_BIAS || MODE == MODE_BF16_BIAS_RELU)
        bval = bias[col];
#pragma unroll
      for (int r = 0; r < 4; ++r) {
        int row = grow0 + i*16 + (lane>>4)*4 + r;
        float v = acc[i][j][r];
        if (MODE == MODE_F32_BIAS) {
          Cf[(size_t)row*ldc + col] = v + bval;
        } else if (MODE == MODE_F32_NOBIAS) {
          Cf[(size_t)row*ldc + col] = v;
        } else {
          v += bval;
          if (MODE == MODE_BF16_BIAS_RELU) v = fmaxf(v, 0.f);
          Ch[(size_t)row*ldc + col] = bf16b(v);
        }
      }
    }
  }
}

// ====== fused attention v2: in-kernel V transpose, P aliased onto Ks (72KB) ======
// grid (4, 192). LDS: Qs 8K + Ks/Ps 32K + Vs 32K = 72KB -> 2 blocks/CU.
__global__ __launch_bounds__(256) void k_attn(
    const unsigned short* __restrict__ qkv,
    const unsigned short* __restrict__ biasb,
    unsigned short* __restrict__ O) {
  __shared__ unsigned short Qs[64*64];
  __shared__ unsigned short Ks[256*64];   // after QK^T, reused as Ps[64][256] (swizzled)
  __shared__ unsigned short Vs[64*256];   // rows = d (64), cols = k (256), swizzled
  unsigned short* Ps = Ks;
  int t = threadIdx.x, lane = t & 63, wid = t >> 6;
  int z = blockIdx.y, n = z / NH, h = z - n*NH;
  int m0 = blockIdx.x * 64;
  const unsigned short* Qb = qkv + (size_t)n*SEQ*QKVN + (size_t)h*DKH + (size_t)m0*QKVN;
  const unsigned short* Kb = qkv + (size_t)n*SEQ*QKVN + H + (size_t)h*DKH;
  const unsigned short* Vb = qkv + (size_t)n*SEQ*QKVN + 2*H + (size_t)h*DKH;
#pragma unroll
  for (int r = 0; r < 2; ++r) {
    int chunk = wid*2 + r;
    int row = chunk*8 + (lane >> 3);
    int col = ((lane & 7) ^ (row & 7)) * 8;
    gload16(Qb + (size_t)row*QKVN + col, &Qs[chunk*512]);
  }
#pragma unroll
  for (int r = 0; r < 8; ++r) {
    int chunk = wid*8 + r;
    int row = chunk*8 + (lane >> 3);
    int col = ((lane & 7) ^ (row & 7)) * 8;
    gload16(Kb + (size_t)row*QKVN + col, &Ks[chunk*512]);
  }
  // V transpose: thread reads V[k][d0..d0+7] for k = kr0 + i*32; writes Vs[d][swz(k)]
  {
    int kr0 = t >> 3, d0 = (t & 7) * 8;
#pragma unroll
    for (int i = 0; i < 8; ++i) {
      int k = kr0 + i*32;
      v8s vv = *(const v8s*)(Vb + (size_t)k*QKVN + d0);
      int kc = k >> 3, ke = k & 7;
#pragma unroll
      for (int j = 0; j < 8; ++j) {
        int d = d0 + j;
        Vs[d*256 + ((kc ^ (d & 7)) << 3) + ke] = (unsigned short)vv[j];
      }
    }
  }
  __syncthreads();

  // ---- QK^T: wave's 16 q-rows x all 256 k-cols ----
  v4f acc[16];
#pragma unroll
  for (int j = 0; j < 16; ++j) acc[j] = (v4f){0.f,0.f,0.f,0.f};
#pragma unroll
  for (int ks = 0; ks < 2; ++ks) {
    int arow = wid*16 + (lane & 15);
    int ac = (ks*4 + (lane >> 4)) ^ (arow & 7);
    v8bf af = *(const v8bf*)&Qs[arow*64 + ac*8];
#pragma unroll
    for (int j = 0; j < 16; ++j) {
      int brow = j*16 + (lane & 15);
      int bc = (ks*4 + (lane >> 4)) ^ (brow & 7);
      v8bf bf = *(const v8bf*)&Ks[brow*64 + bc*8];
      acc[j] = __builtin_amdgcn_mfma_f32_16x16x32_bf16(af, bf, acc[j], 0, 0, 0);
    }
  }

  // ---- scale + bias + row softmax (16-lane groups) ----
  int col = lane & 15, quad = lane >> 4;
  const unsigned short* bb = biasb + (size_t)n*65536;
  float e[16][4];
  float rm[4] = {-1e30f, -1e30f, -1e30f, -1e30f};
#pragma unroll
  for (int r = 0; r < 4; ++r) {
    int row = m0 + wid*16 + quad*4 + r;
#pragma unroll
    for (int j = 0; j < 16; ++j) {
      float v = acc[j][r]*0.125f + b2f(bb[(size_t)row*256 + j*16 + col]);
      e[j][r] = v;
      rm[r] = fmaxf(rm[r], v);
    }
  }
#pragma unroll
  for (int r = 0; r < 4; ++r)
#pragma unroll
    for (int m = 1; m < 16; m <<= 1) rm[r] = fmaxf(rm[r], __shfl_xor(rm[r], m, 64));
  float rs[4] = {0.f, 0.f, 0.f, 0.f};
#pragma unroll
  for (int r = 0; r < 4; ++r)
#pragma unroll
    for (int j = 0; j < 16; ++j) {
      float ev = __expf(e[j][r] - rm[r]);
      e[j][r] = ev;
      rs[r] += ev;
    }
#pragma unroll
  for (int r = 0; r < 4; ++r) {
#pragma unroll
    for (int m = 1; m < 16; m <<= 1) rs[r] += __shfl_xor(rs[r], m, 64);
    rs[r] = 1.0f/rs[r];
  }

  __syncthreads();   // all waves done reading Ks before P overwrites it

  // ---- P -> LDS (own 16 rows, involutive chunk swizzle) ----
#pragma unroll
  for (int r = 0; r < 4; ++r) {
    int row = wid*16 + quad*4 + r;
#pragma unroll
    for (int j = 0; j < 16; ++j) {
      int cc = j*2 + (col >> 3);
      Ps[row*256 + ((cc ^ (row & 7))*8) + (col & 7)] = bf16b(e[j][r]*rs[r]);
    }
  }
  asm volatile("s_waitcnt lgkmcnt(0)" ::: "memory");
  __builtin_amdgcn_sched_barrier(0);

  // ---- PV: O[16 rows][64 d-cols], K=256 ----
  v4f po[4];
#pragma unroll
  for (int j = 0; j < 4; ++j) po[j] = (v4f){0.f,0.f,0.f,0.f};
#pragma unroll
  for (int kk = 0; kk < 8; ++kk) {
    int arow = wid*16 + (lane & 15);
    int c = kk*4 + (lane >> 4);
    v8bf af = *(const v8bf*)&Ps[arow*256 + ((c ^ (arow & 7))*8)];
#pragma unroll
    for (int j = 0; j < 4; ++j) {
      int brow = j*16 + (lane & 15);
      v8bf bf = *(const v8bf*)&Vs[brow*256 + ((c ^ (brow & 7))*8)];
      po[j] = __builtin_amdgcn_mfma_f32_16x16x32_bf16(af, bf, po[j], 0, 0, 0);
    }
  }

  unsigned short* Ob = O + ((size_t)n*SEQ + m0)*H + (size_t)h*DKH;
#pragma unroll
  for (int j = 0; j < 4; ++j) {
    int ocol = j*16 + (lane & 15);
#pragma unroll
    for (int r = 0; r < 4; ++r) {
      int orow = wid*16 + quad*4 + r;
      Ob[(size_t)orow*H + ocol] = bf16b(po[j][r]);
    }
  }
}

// ============ weight transpose+cast ============
__global__ __launch_bounds__(256) void k_wT(const float* __restrict__ in,
                                            unsigned short* __restrict__ out,
                                            int Nn, int Kk) {
  int n0 = blockIdx.x*64, k0 = blockIdx.y*64;
  __shared__ float T[64][72];
  int t = threadIdx.x;
  int r = t >> 4, c4 = (t & 15) * 4;
#pragma unroll
  for (int i = 0; i < 4; ++i) {
    float4 v = *(const float4*)(in + (size_t)(k0 + r + i*16)*Nn + n0 + c4);
    T[c4+0][r+i*16] = v.x; T[c4+1][r+i*16] = v.y;
    T[c4+2][r+i*16] = v.z; T[c4+3][r+i*16] = v.w;
  }
  __syncthreads();
  int c = t >> 3, r8 = (t & 7) * 8;
#pragma unroll
  for (int i = 0; i < 2; ++i) {
    int cc = c + i*32;
    v8s o;
#pragma unroll
    for (int j = 0; j < 8; ++j) o[j] = (short)bf16b(T[cc][r8+j]);
    *(v8s*)(out + (size_t)(n0+cc)*Kk + k0 + r8) = o;
  }
}

__global__ void k_bqkv(const float* __restrict__ bq, const float* __restrict__ bk,
                       const float* __restrict__ bv, float* __restrict__ o) {
  int i = blockIdx.x*256 + threadIdx.x;
  if (i >= 3*QKVN) return;
  int l = i / QKVN, j = i - l*QKVN;
  float v = (j < H) ? bq[l*H + j] : (j < 2*H) ? bk[l*H + j - H] : bv[l*H + j - 2*H];
  o[i] = v;
}

__global__ __launch_bounds__(256) void k_cast(const float* __restrict__ x,
                                              float* __restrict__ enc,
                                              unsigned short* __restrict__ enc16) {
  size_t i = ((size_t)blockIdx.x*256 + threadIdx.x)*4;
  float4 v = *(const float4*)(x + i);
  *(float4*)(enc + i) = v;
  ushort4 u = { bf16b(v.x), bf16b(v.y), bf16b(v.z), bf16b(v.w) };
  *(ushort4*)(enc16 + i) = u;
}

__global__ __launch_bounds__(256) void k_fusion_weights(
    const float* __restrict__ x, const float* __restrict__ lin_w,
    const float* __restrict__ lin_b, float* __restrict__ wsoft) {
  int n = blockIdx.x, t = threadIdx.x;
  __shared__ float xm[H];
  __shared__ float sred[4];
  __shared__ float logits[12];
  if (t < 192) {
    const float4* p = (const float4*)(x + (size_t)n*SEQ*H) + t;
    float4 s = {0.f,0.f,0.f,0.f};
    for (int r = 0; r < SEQ; ++r) {
      float4 v = p[(size_t)r*192];
      s.x += v.x; s.y += v.y; s.z += v.z; s.w += v.w;
    }
    xm[t*4+0] = s.x*(1.0f/SEQ); xm[t*4+1] = s.y*(1.0f/SEQ);
    xm[t*4+2] = s.z*(1.0f/SEQ); xm[t*4+3] = s.w*(1.0f/SEQ);
  }
  __syncthreads();
  float lacc[12];
#pragma unroll
  for (int j = 0; j < 12; ++j) lacc[j] = 0.f;
  for (int hh = t; hh < H; hh += 256) {
    float xv = xm[hh];
#pragma unroll
    for (int j = 0; j < 12; ++j) lacc[j] += xv * lin_w[hh*12 + j];
  }
  for (int j = 0; j < 12; ++j) {
    float v = lacc[j];
#pragma unroll
    for (int m = 1; m < 64; m <<= 1) v += __shfl_xor(v, m, 64);
    if ((t & 63) == 0) sred[t >> 6] = v;
    __syncthreads();
    if (t == 0) logits[j] = sred[0]+sred[1]+sred[2]+sred[3] + lin_b[j];
    __syncthreads();
  }
  if (t < 3) {
    int l = t;
    float mx = -1e30f;
    for (int m = 0; m < 4; ++m) mx = fmaxf(mx, logits[l*4+m]);
    float e[4], s = 0.f;
    for (int m = 0; m < 4; ++m) { e[m] = expf(logits[l*4+m]-mx); s += e[m]; }
    for (int m = 0; m < 4; ++m) wsoft[(l*NSEQ + n)*4 + m] = e[m]/s;
  }
}

// mask fusion -> bf16 bias
__global__ __launch_bounds__(256) void k_bias(
    const float* __restrict__ cm, const float* __restrict__ dm,
    const float* __restrict__ ent, const float* __restrict__ sm,
    const float* __restrict__ wsoft, int l, unsigned short* __restrict__ bias) {
  int g = blockIdx.x*256 + threadIdx.x;
  int n = g >> 14;
  int k4 = g & 63;
  const float* w = wsoft + (l*NSEQ + n)*4;
  float w0 = w[0], w1 = w[1], w2 = w[2], w3 = w[3];
  float4 c = ((const float4*)cm)[g];
  float4 d = ((const float4*)dm)[g];
  float4 s = ((const float4*)sm)[g];
  float4 e = ((const float4*)(ent + (size_t)n*SEQ))[k4];
  ushort4 o;
  o.x = bf16b(w0*c.x + w1*d.x + w2*e.x + w3*s.x);
  o.y = bf16b(w0*c.y + w1*d.y + w2*e.y + w3*s.y);
  o.z = bf16b(w0*c.z + w1*d.z + w2*e.z + w3*s.z);
  o.w = bf16b(w0*c.w + w1*d.w + w2*e.w + w3*s.w);
  ((ushort4*)bias)[g] = o;
}

__global__ void k_nonpad(const int* __restrict__ ids, float* __restrict__ npad) {
  int i = blockIdx.x*256 + threadIdx.x;
  if (i < MROWS) npad[i] = (ids[i] != 1) ? 1.0f : 0.0f;
}

__global__ __launch_bounds__(256) void k_ln(
    const float* __restrict__ f, float* __restrict__ enc,
    unsigned short* __restrict__ enc16,
    const float* __restrict__ g, const float* __restrict__ b,
    const float* __restrict__ npad) {
  int r = blockIdx.x, t = threadIdx.x;
  size_t base = (size_t)r*H;
  float v0 = f[base+t]     + enc[base+t];
  float v1 = f[base+t+256] + enc[base+t+256];
  float v2 = f[base+t+512] + enc[base+t+512];
  __shared__ float sred[4];
  float s = v0+v1+v2;
#pragma unroll
  for (int m = 1; m < 64; m <<= 1) s += __shfl_xor(s, m, 64);
  if ((t & 63) == 0) sred[t >> 6] = s;
  __syncthreads();
  float mean = (sred[0]+sred[1]+sred[2]+sred[3]) * (1.0f/H);
  __syncthreads();
  float d0 = v0-mean, d1 = v1-mean, d2 = v2-mean;
  float ss = d0*d0 + d1*d1 + d2*d2;
#pragma unroll
  for (int m = 1; m < 64; m <<= 1) ss += __shfl_xor(ss, m, 64);
  if ((t & 63) == 0) sred[t >> 6] = ss;
  __syncthreads();
  float var = (sred[0]+sred[1]+sred[2]+sred[3]) * (1.0f/H);
  float rstd = 1.0f/sqrtf(var + 1e-5f);
  float npv = npad[r];
  float o0 = (g[t]    *d0*rstd + b[t]    )*npv;
  float o1 = (g[t+256]*d1*rstd + b[t+256])*npv;
  float o2 = (g[t+512]*d2*rstd + b[t+512])*npv;
  enc[base+t]     = o0; enc[base+t+256] = o1; enc[base+t+512] = o2;
  enc16[base+t]     = bf16b(o0);
  enc16[base+t+256] = bf16b(o1);
  enc16[base+t+512] = bf16b(o2);
}

// ====== LN over sum of 2 split-K partials + column bias + residual ======
__global__ __launch_bounds__(256) void k_ln2(
    const float* __restrict__ p, float* __restrict__ enc,
    unsigned short* __restrict__ enc16,
    const float* __restrict__ g, const float* __restrict__ b,
    const float* __restrict__ npad, const float* __restrict__ cbias) {
  int r = blockIdx.x, t = threadIdx.x;
  size_t base = (size_t)r*H;
  const size_t PS = (size_t)MROWS*H;
  float v0 = p[base+t]     + p[PS+base+t]     + cbias[t]     + enc[base+t];
  float v1 = p[base+t+256] + p[PS+base+t+256] + cbias[t+256] + enc[base+t+256];
  float v2 = p[base+t+512] + p[PS+base+t+512] + cbias[t+512] + enc[base+t+512];
  __shared__ float sred[4];
  float s = v0+v1+v2;
#pragma unroll
  for (int m = 1; m < 64; m <<= 1) s += __shfl_xor(s, m, 64);
  if ((t & 63) == 0) sred[t >> 6] = s;
  __syncthreads();
  float mean = (sred[0]+sred[1]+sred[2]+sred[3]) * (1.0f/H);
  __syncthreads();
  float d0 = v0-mean, d1 = v1-mean, d2 = v2-mean;
  float ss = d0*d0 + d1*d1 + d2*d2;
#pragma unroll
  for (int m = 1; m < 64; m <<= 1) ss += __shfl_xor(ss, m, 64);
  if ((t & 63) == 0) sred[t >> 6] = ss;
  __syncthreads();
  float var = (sred[0]+sred[1]+sred[2]+sred[3]) * (1.0f/H);
  float rstd = 1.0f/sqrtf(var + 1e-5f);
  float npv = npad[r];
  float o0 = (g[t]    *d0*rstd + b[t]    )*npv;
  float o1 = (g[t+256]*d1*rstd + b[t+256])*npv;
  float o2 = (g[t+512]*d2*rstd + b[t+512])*npv;
  enc[base+t]     = o0; enc[base+t+256] = o1; enc[base+t+512] = o2;
  enc16[base+t]     = bf16b(o0);
  enc16[base+t+256] = bf16b(o1);
  enc16[base+t+512] = bf16b(o2);
}

__global__ __launch_bounds__(256) void k_colstats(
    const float* __restrict__ enc, float* __restrict__ csum, float* __restrict__ csq) {
  int r0 = blockIdx.x*16, t = threadIdx.x;
  float s0=0,s1=0,s2=0,q0=0,q1=0,q2=0;
  for (int r = 0; r < 16; ++r) {
    const float* row = enc + (size_t)(r0+r)*H;
    float a = row[t], b = row[t+256], c = row[t+512];
    s0 += a; s1 += b; s2 += c;
    q0 += a*a; q1 += b*b; q2 += c*c;
  }
  atomicAdd(&csum[t],     s0); atomicAdd(&csum[t+256], s1); atomicAdd(&csum[t+512], s2);
  atomicAdd(&csq[t],      q0); atomicAdd(&csq[t+256],  q1); atomicAdd(&csq[t+512],  q2);
}

__global__ __launch_bounds__(256) void k_poolprep(
    const float* __restrict__ x, const float* __restrict__ enc,
    const float* __restrict__ csum, const float* __restrict__ csq,
    const float* __restrict__ bnt_g, const float* __restrict__ bnt_b,
    float* __restrict__ ps0) {
  int n = blockIdx.x, t = threadIdx.x;
  for (int hh = t; hh < H; hh += 256) {
    float m = csum[hh] * (1.0f/MROWS);
    float var = csq[hh] * (1.0f/MROWS) - m*m;
    float rstd = 1.0f/sqrtf(var + 1e-5f);
    float e = enc[(size_t)n*SEQ*H + hh];
    ps0[n*H + hh] = x[(size_t)n*SEQ*H + hh] + bnt_g[hh]*(e-m)*rstd + bnt_b[hh];
  }
}

__global__ __launch_bounds__(256) void k_poolmm(
    const float* __restrict__ ps0, const float* __restrict__ pool_w,
    const float* __restrict__ pool_b, float* __restrict__ pooled) {
  int n = blockIdx.y, jb = blockIdx.x*64;
  __shared__ float s0[H];
  __shared__ float part[4][64];
  int t = threadIdx.x;
  for (int hh = t; hh < H; hh += 256) s0[hh] = ps0[n*H + hh];
  __syncthreads();
  int j = t & 63, q = t >> 6;
  float a = 0.f;
  int h0 = q*192;
  for (int hh = h0; hh < h0+192; ++hh)
    a = fmaf(s0[hh], pool_w[(size_t)hh*H + jb + j], a);
  part[q][j] = a;
  __syncthreads();
  if (t < 64) {
    float v = part[0][t]+part[1][t]+part[2][t]+part[3][t] + pool_b[jb+t];
    pooled[n*H + jb + t] = tanhf(v);
  }
}

__global__ __launch_bounds__(256) void k_final(
    const float* __restrict__ pooled, const float* __restrict__ bn_g,
    const float* __restrict__ bn_b, const float* __restrict__ cls_w,
    const float* __restrict__ cls_b, float* __restrict__ out) {
  int t = threadIdx.x;
  float acc[16];
#pragma unroll
  for (int n = 0; n < 16; ++n) acc[n] = 0.f;
  for (int hh = t; hh < H; hh += 256) {
    float p[16]; float m = 0.f;
#pragma unroll
    for (int n = 0; n < 16; ++n) { p[n] = pooled[n*H + hh]; m += p[n]; }
    m *= (1.0f/16.f);
    float var = 0.f;
#pragma unroll
    for (int n = 0; n < 16; ++n) { float d = p[n]-m; var += d*d; }
    var *= (1.0f/16.f);
    float rstd = 1.0f/sqrtf(var + 1e-5f);
    float gw = bn_g[hh]*rstd*cls_w[hh];
    float off = bn_b[hh]*cls_w[hh];
#pragma unroll
    for (int n = 0; n < 16; ++n) acc[n] += (p[n]-m)*gw + off;
  }
  __shared__ float sred[4];
  for (int n = 0; n < 16; ++n) {
    float v = acc[n];
#pragma unroll
    for (int m = 1; m < 64; m <<= 1) v += __shfl_xor(v, m, 64);
    if ((t & 63) == 0) sred[t >> 6] = v;
    __syncthreads();
    if (t == 0) out[n] = sred[0]+sred[1]+sred[2]+sred[3] + cls_b[0];
    __syncthreads();
  }
}

extern "C" void kernel_launch(void* const* d_in, const int* in_sizes, int n_in,
                              void* d_out, int out_size, void* d_ws, size_t ws_size,
                              hipStream_t stream) {
  const int*   input_ids = (const int*)  d_in[0];
  const float* x       = (const float*)d_in[1];
  const float* cm      = (const float*)d_in[3];
  const float* dm      = (const float*)d_in[4];
  const float* ent     = (const float*)d_in[5];
  const float* sm      = (const float*)d_in[6];
  const float* lin_w   = (const float*)d_in[7];
  const float* lin_b   = (const float*)d_in[8];
  const float* Wq      = (const float*)d_in[9];
  const float* bq      = (const float*)d_in[10];
  const float* Wk      = (const float*)d_in[11];
  const float* bk      = (const float*)d_in[12];
  const float* Wv      = (const float*)d_in[13];
  const float* bv      = (const float*)d_in[14];
  const float* Wo      = (const float*)d_in[15];
  const float* bo      = (const float*)d_in[16];
  const float* ln1_g   = (const float*)d_in[17];
  const float* ln1_b   = (const float*)d_in[18];
  const float* W1      = (const float*)d_in[19];
  const float* b1      = (const float*)d_in[20];
  const float* W2      = (const float*)d_in[21];
  const float* b2      = (const float*)d_in[22];
  const float* ln2_g   = (const float*)d_in[23];
  const float* ln2_b   = (const float*)d_in[24];
  const float* bnt_g   = (const float*)d_in[25];
  const float* bnt_b   = (const float*)d_in[26];
  const float* pool_w  = (const float*)d_in[27];
  const float* pool_b  = (const float*)d_in[28];
  const float* bn_g    = (const float*)d_in[29];
  const float* bn_b    = (const float*)d_in[30];
  const float* cls_w   = (const float*)d_in[31];
  const float* cls_b   = (const float*)d_in[32];
  float* out = (float*)d_out;
  (void)ws_size; (void)n_in; (void)in_sizes; (void)out_size;

  char* wsb = (char*)d_ws;
  size_t off = 0;
  auto alloc = [&](size_t bytes) {
    void* p = (void*)(wsb + off);
    off += (bytes + 255) & ~(size_t)255;
    return p;
  };
  float* enc            = (float*)alloc((size_t)MROWS*H*4);
  unsigned short* enc16 = (unsigned short*)alloc((size_t)MROWS*H*2);
  unsigned short* qkv16 = (unsigned short*)alloc((size_t)MROWS*QKVN*2);
  unsigned short* ob16  = (unsigned short*)alloc((size_t)MROWS*H*2);
  float* fbuf           = (float*)alloc((size_t)2*MROWS*H*4);
  unsigned short* PH    = (unsigned short*)alloc((size_t)MROWS*DI*2);
  unsigned short* hidden16 = PH;
  unsigned short* biasb = (unsigned short*)alloc((size_t)NSEQ*SEQ*SEQ*2);
  unsigned short* WqkvT = (unsigned short*)alloc((size_t)3*QKVN*H*2);
  unsigned short* WoT   = (unsigned short*)alloc((size_t)3*H*H*2);
  unsigned short* W1T   = (unsigned short*)alloc((size_t)3*DI*H*2);
  unsigned short* W2T   = (unsigned short*)alloc((size_t)3*H*DI*2);
  float* bqkv   = (float*)alloc(3*QKVN*4);
  float* wsoft  = (float*)alloc(3*16*4*4);
  float* npad   = (float*)alloc(MROWS*4);
  float* csum   = (float*)alloc(H*4);
  float* csq    = (float*)alloc(H*4);
  float* ps0    = (float*)alloc(16*H*4);
  float* pooled = (float*)alloc(16*H*4);

  k_cast<<<MROWS*H/1024, 256, 0, stream>>>(x, enc, enc16);
  k_fusion_weights<<<16, 256, 0, stream>>>(x, lin_w, lin_b, wsoft);
  k_nonpad<<<MROWS/256, 256, 0, stream>>>(input_ids, npad);
  k_bqkv<<<27, 256, 0, stream>>>(bq, bk, bv, bqkv);
  for (int l = 0; l < 3; ++l) {
    k_wT<<<dim3(12,12), 256, 0, stream>>>(Wq + (size_t)l*H*H, WqkvT + (size_t)l*QKVN*H,           H, H);
    k_wT<<<dim3(12,12), 256, 0, stream>>>(Wk + (size_t)l*H*H, WqkvT + (size_t)l*QKVN*H + H*H,     H, H);
    k_wT<<<dim3(12,12), 256, 0, stream>>>(Wv + (size_t)l*H*H, WqkvT + (size_t)l*QKVN*H + 2*H*H,   H, H);
    k_wT<<<dim3(12,12), 256, 0, stream>>>(Wo + (size_t)l*H*H, WoT + (size_t)l*H*H,                H, H);
    k_wT<<<dim3(64,12), 256, 0, stream>>>(W1 + (size_t)l*H*DI, W1T + (size_t)l*DI*H,              DI, H);
    k_wT<<<dim3(12,64), 256, 0, stream>>>(W2 + (size_t)l*DI*H, W2T + (size_t)l*H*DI,              H, DI);
  }

  for (int l = 0; l < 3; ++l) {
    k_bias<<<1024, 256, 0, stream>>>(cm, dm, ent, sm, wsoft, l, biasb);
    // QKV: 128x128, BK=32, depth-2 counted
    k_mm<128,128,MODE_BF16_BIAS,32,2,true><<<dim3(18,32,1), 256, 0, stream>>>(
        enc16, H, 0, 0, WqkvT + (size_t)l*QKVN*H, H, 0, 0,
        qkv16, QKVN, 0, 0, bqkv + l*QKVN, H, 1);
    // fused attention v2 (in-kernel V^T, P aliases Ks, 72KB LDS)
    k_attn<<<dim3(4,192), 256, 0, stream>>>(qkv16, biasb, ob16);
    // Wo (64x64 BK=64 depth-3 + swizzle)
    k_mm<64,64,MODE_F32_BIAS,64,3,true><<<dim3(12,64,1), 256, 0, stream>>>(
        ob16, H, 0, 0, WoT + (size_t)l*H*H, H, 0, 0,
        fbuf, H, 0, 0, bo + l*H, H, 1);
    k_ln<<<MROWS, 256, 0, stream>>>(fbuf, enc, enc16, ln1_g + l*H, ln1_b + l*H, npad);
    // W1 + ReLU: 256x256 8-wave dbuf-counted
    k_mm256<MODE_BF16_BIAS_RELU><<<dim3(16,16), 512, 131072, stream>>>(
        enc16, H, W1T + (size_t)l*DI*H, H, hidden16, DI, b1 + l*DI, H);
    // W2: split-K2, 128x64 tiles, BK=32, depth-2 counted (grid 12x32x2 = 768)
    k_mm<128,64,MODE_F32_NOBIAS,32,2,true><<<dim3(12,32,2), 256, 0, stream>>>(
        hidden16, DI, 0, 2048, W2T + (size_t)l*H*DI, DI, 0, 2048,
        fbuf, H, 0, (long long)MROWS*H, nullptr, 2048, 2);
    k_ln2<<<MROWS, 256, 0, stream>>>(fbuf, enc, enc16, ln2_g + l*H, ln2_b + l*H, npad, b2 + l*H);
  }

  hipMemsetAsync(csum, 0, H*sizeof(float), stream);
  hipMemsetAsync(csq,  0, H*sizeof(float), stream);
  k_colstats<<<256, 256, 0, stream>>>(enc, csum, csq);
  k_poolprep<<<16, 256, 0, stream>>>(x, enc, csum, csq, bnt_g, bnt_b, ps0);
  k_poolmm<<<dim3(12,16), 256, 0, stream>>>(ps0, pool_w, pool_b, pooled);
  k_final<<<1, 256, 0, stream>>>(pooled, bn_g, bn_b, cls_w, cls_b, out);
}

// Round 13
// 616.637 us; speedup vs baseline: 1.0624x; 1.0349x over previous
//
#include <hip/hip_runtime.h>
#include <hip/hip_bf16.h>
#include <math.h>

#define NSEQ 16
#define SEQ 256
#define H 768
#define NH 12
#define DKH 64
#define DI 4096
#define MROWS (NSEQ*SEQ)   // 4096
#define QKVN (3*H)         // 2304

typedef __bf16 v8bf __attribute__((ext_vector_type(8)));
typedef float  v4f  __attribute__((ext_vector_type(4)));
typedef short  v8s  __attribute__((ext_vector_type(8)));

__device__ inline unsigned short bf16b(float f) {
  __hip_bfloat16 h = __float2bfloat16(f);
  return *reinterpret_cast<unsigned short*>(&h);
}
__device__ inline float b2f(unsigned short b) {
  return __uint_as_float(((unsigned int)b) << 16);
}

__device__ __forceinline__ void gload16(const void* g, void* l) {
  __builtin_amdgcn_global_load_lds((const __attribute__((address_space(1))) void*)g,
                                   (__attribute__((address_space(3))) void*)l, 16, 0, 0);
}

__device__ __forceinline__ void waitvm(int n) {
  switch (n) {
    case 0:  asm volatile("s_waitcnt vmcnt(0)" ::: "memory"); break;
    case 2:  asm volatile("s_waitcnt vmcnt(2)" ::: "memory"); break;
    case 4:  asm volatile("s_waitcnt vmcnt(4)" ::: "memory"); break;
    case 8:  asm volatile("s_waitcnt vmcnt(8)" ::: "memory"); break;
    case 12: asm volatile("s_waitcnt vmcnt(12)" ::: "memory"); break;
    case 16: asm volatile("s_waitcnt vmcnt(16)" ::: "memory"); break;
    default: asm volatile("s_waitcnt vmcnt(0)" ::: "memory"); break;
  }
}

enum { MODE_F32_BIAS=0, MODE_BF16_BIAS=1, MODE_BF16_BIAS_RELU=2, MODE_SCORES=3, MODE_PV=4, MODE_F32_NOBIAS=5 };

// ================= bf16 MFMA GEMM (4 waves), BK parameterized =================
template<int BM, int BN, int MODE, int BK, int DEPTH, bool SWZ>
__global__ __launch_bounds__(256) void k_mm(
    const unsigned short* __restrict__ A, int lda, long long saN, long long saH,
    const unsigned short* __restrict__ B, int ldb, long long sbN, long long sbH,
    void* __restrict__ Cout, int ldc, long long scN, long long scH,
    const float* __restrict__ bias, int K, int nhdiv) {
  constexpr int MI = BM/32, NI = BN/32;
  constexpr int CH  = BK/8;
  constexpr int RPC = 512/BK;
  constexpr int SW  = CH - 1;
  constexpr int SSH = (BK == 32) ? 1 : 0;
  constexpr int AISS = BM*BK/2048, BISS = BN*BK/2048;
  constexpr int LPT = AISS + BISS;
  constexpr int TA = BM*BK, TB = BN*BK;
  __shared__ unsigned short As[DEPTH*TA];
  __shared__ unsigned short Bs[DEPTH*TB];
  int t = threadIdx.x;
  int z = blockIdx.z, n = z / nhdiv, h = z - n*nhdiv;
  int lane = t & 63, wid = t >> 6, wr = wid >> 1, wc = wid & 1;

  int bx = blockIdx.x, by = blockIdx.y;
  if (SWZ) {
    int gx = gridDim.x;
    int nwg = gx * gridDim.y;
    int lin = by*gx + bx;
    int q = nwg >> 3, r = nwg & 7;
    int xcd = lin & 7, idx = lin >> 3;
    int swz = (xcd < r) ? (xcd*(q+1) + idx) : (r*(q+1) + (xcd-r)*q + idx);
    bx = swz % gx; by = swz / gx;
  }

  const unsigned short* Ab = A + (size_t)n*saN + (size_t)h*saH + (size_t)by*BM*lda;
  const unsigned short* Bb = B + (size_t)n*sbN + (size_t)h*sbH + (size_t)bx*BN*ldb;

  const unsigned short* aSrc[AISS]; int aOff[AISS];
#pragma unroll
  for (int r = 0; r < AISS; ++r) {
    int chunk = wid*AISS + r;
    int row = chunk*RPC + lane/CH;
    int col = ((lane % CH) ^ ((row >> SSH) & SW)) * 8;
    aSrc[r] = Ab + (size_t)row*lda + col;
    aOff[r] = chunk*512;
  }
  const unsigned short* bSrc[BISS]; int bOff[BISS];
#pragma unroll
  for (int r = 0; r < BISS; ++r) {
    int chunk = wid*BISS + r;
    int row = chunk*RPC + lane/CH;
    int col = ((lane % CH) ^ ((row >> SSH) & SW)) * 8;
    bSrc[r] = Bb + (size_t)row*ldb + col;
    bOff[r] = chunk*512;
  }

  v4f acc[MI][NI];
#pragma unroll
  for (int i = 0; i < MI; ++i)
#pragma unroll
    for (int j = 0; j < NI; ++j) acc[i][j] = (v4f){0.f,0.f,0.f,0.f};

  auto issue = [&](int tt, int buf) {
    int k0 = tt * BK;
#pragma unroll
    for (int r = 0; r < AISS; ++r) gload16(aSrc[r] + k0, &As[buf*TA + aOff[r]]);
#pragma unroll
    for (int r = 0; r < BISS; ++r) gload16(bSrc[r] + k0, &Bs[buf*TB + bOff[r]]);
  };

  int nt = K / BK;
  for (int p = 0; p < DEPTH-1 && p < nt; ++p) issue(p, p);
  int cbuf = 0;
  int ibuf = (DEPTH-1) % DEPTH;
  for (int tt = 0; tt < nt; ++tt) {
    int ahead = tt + DEPTH - 1;
    if (ahead < nt) {
      issue(ahead, ibuf);
      waitvm((DEPTH-1)*LPT);
    } else {
      waitvm((nt-1-tt)*LPT);
    }
    __builtin_amdgcn_s_barrier();
    asm volatile("" ::: "memory");
#pragma unroll
    for (int ks = 0; ks < BK/32; ++ks) {
      v8bf af[MI], bfr[NI];
#pragma unroll
      for (int i = 0; i < MI; ++i) {
        int row = wr*(BM/2) + i*16 + (lane & 15);
        int c = (ks*4 + (lane >> 4)) ^ ((row >> SSH) & SW);
        af[i] = *(const v8bf*)&As[cbuf*TA + row*BK + c*8];
      }
#pragma unroll
      for (int j = 0; j < NI; ++j) {
        int row = wc*(BN/2) + j*16 + (lane & 15);
        int c = (ks*4 + (lane >> 4)) ^ ((row >> SSH) & SW);
        bfr[j] = *(const v8bf*)&Bs[cbuf*TB + row*BK + c*8];
      }
#pragma unroll
      for (int i = 0; i < MI; ++i)
#pragma unroll
        for (int j = 0; j < NI; ++j)
          acc[i][j] = __builtin_amdgcn_mfma_f32_16x16x32_bf16(af[i], bfr[j], acc[i][j], 0, 0, 0);
    }
    asm volatile("s_waitcnt lgkmcnt(0)" ::: "memory");
    __builtin_amdgcn_s_barrier();
    asm volatile("" ::: "memory");
    cbuf = (cbuf + 1 == DEPTH) ? 0 : cbuf + 1;
    ibuf = (ibuf + 1 == DEPTH) ? 0 : ibuf + 1;
  }

  float* Cf = (float*)Cout;
  unsigned short* Ch = (unsigned short*)Cout;
  size_t cb = (size_t)n*scN + (size_t)h*scH;
  int grow0 = by*BM + wr*(BM/2);
  int gcol0 = bx*BN + wc*(BN/2);
#pragma unroll
  for (int i = 0; i < MI; ++i) {
#pragma unroll
    for (int j = 0; j < NI; ++j) {
      int col = gcol0 + j*16 + (lane & 15);
      float bval = 0.f;
      if (MODE == MODE_F32_BIAS || MODE == MODE_BF16_BIAS || MODE == MODE_BF16_BIAS_RELU)
        bval = bias[col];
#pragma unroll
      for (int r = 0; r < 4; ++r) {
        int row = grow0 + i*16 + (lane>>4)*4 + r;
        float v = acc[i][j][r];
        if (MODE == MODE_F32_BIAS) {
          Cf[cb + (size_t)row*ldc + col] = v + bval;
        } else if (MODE == MODE_F32_NOBIAS) {
          Cf[cb + (size_t)row*ldc + col] = v;
        } else if (MODE == MODE_PV) {
          Ch[cb + (size_t)row*ldc + col] = bf16b(v);
        } else {
          v += bval;
          if (MODE == MODE_BF16_BIAS_RELU) v = fmaxf(v, 0.f);
          Ch[cb + (size_t)row*ldc + col] = bf16b(v);
        }
      }
    }
  }
}

// ================= 256x256 / 8-wave / BK64 dbuf-counted GEMM =================
template<int MODE>
__global__ __launch_bounds__(512) void k_mm256(
    const unsigned short* __restrict__ A, int lda,
    const unsigned short* __restrict__ B, int ldb,
    void* __restrict__ Cout, int ldc,
    const float* __restrict__ bias, int K) {
  extern __shared__ __align__(16) unsigned short smem[];
  unsigned short* As = smem;
  unsigned short* Bs = smem + 2*16384;
  constexpr int TA = 256*64;
  int t = threadIdx.x, lane = t & 63, wid = t >> 6;
  int wr = wid >> 2, wc = wid & 3;

  int bx = blockIdx.x, by = blockIdx.y;
  {
    int gx = gridDim.x, nwg = gx * gridDim.y;
    int lin = by*gx + bx;
    int q = nwg >> 3, r = nwg & 7;
    int xcd = lin & 7, idx = lin >> 3;
    int swz = (xcd < r) ? (xcd*(q+1) + idx) : (r*(q+1) + (xcd-r)*q + idx);
    bx = swz % gx; by = swz / gx;
  }

  const unsigned short* Ab = A + (size_t)by*256*lda;
  const unsigned short* Bb = B + (size_t)bx*256*ldb;

  const unsigned short* aSrc[4]; int aOff[4];
  const unsigned short* bSrc[4]; int bOff[4];
#pragma unroll
  for (int r = 0; r < 4; ++r) {
    int chunk = wid*4 + r;
    int row = chunk*8 + (lane >> 3);
    int col = ((lane & 7) ^ (row & 7)) * 8;
    aSrc[r] = Ab + (size_t)row*lda + col;
    bSrc[r] = Bb + (size_t)row*ldb + col;
    aOff[r] = chunk*512;
    bOff[r] = chunk*512;
  }

  v4f acc[8][4];
#pragma unroll
  for (int i = 0; i < 8; ++i)
#pragma unroll
    for (int j = 0; j < 4; ++j) acc[i][j] = (v4f){0.f,0.f,0.f,0.f};

  auto issue = [&](int tt, int buf) {
    int k0 = tt << 6;
#pragma unroll
    for (int r = 0; r < 4; ++r) gload16(aSrc[r] + k0, &As[buf*TA + aOff[r]]);
#pragma unroll
    for (int r = 0; r < 4; ++r) gload16(bSrc[r] + k0, &Bs[buf*TA + bOff[r]]);
  };

  int nt = K >> 6;
  issue(0, 0);
  int cur = 0;
  for (int tt = 0; tt < nt; ++tt) {
    if (tt + 1 < nt) {
      issue(tt+1, cur^1);
      waitvm(8);
    } else {
      waitvm(0);
    }
    __builtin_amdgcn_s_barrier();
    asm volatile("" ::: "memory");
    __builtin_amdgcn_s_setprio(1);
#pragma unroll
    for (int ks = 0; ks < 2; ++ks) {
      v8bf af[8], bfr[4];
#pragma unroll
      for (int i = 0; i < 8; ++i) {
        int row = wr*128 + i*16 + (lane & 15);
        int c = (ks*4 + (lane >> 4)) ^ (row & 7);
        af[i] = *(const v8bf*)&As[cur*TA + row*64 + c*8];
      }
#pragma unroll
      for (int j = 0; j < 4; ++j) {
        int row = wc*64 + j*16 + (lane & 15);
        int c = (ks*4 + (lane >> 4)) ^ (row & 7);
        bfr[j] = *(const v8bf*)&Bs[cur*TA + row*64 + c*8];
      }
#pragma unroll
      for (int i = 0; i < 8; ++i)
#pragma unroll
        for (int j = 0; j < 4; ++j)
          acc[i][j] = __builtin_amdgcn_mfma_f32_16x16x32_bf16(af[i], bfr[j], acc[i][j], 0, 0, 0);
    }
    __builtin_amdgcn_s_setprio(0);
    asm volatile("s_waitcnt lgkmcnt(0)" ::: "memory");
    __builtin_amdgcn_s_barrier();
    asm volatile("" ::: "memory");
    cur ^= 1;
  }

  float* Cf = (float*)Cout;
  unsigned short* Ch = (unsigned short*)Cout;
  int grow0 = by*256 + wr*128;
  int gcol0 = bx*256 + wc*64;
#pragma unroll
  for (int i = 0; i < 8; ++i) {
#pragma unroll
    for (int j = 0; j < 4; ++j) {
      int col = gcol0 + j*16 + (lane & 15);
      float bval = 0.f;
      if (MODE == MODE_F32_BIAS || MODE == MODE_BF16_BIAS || MODE == MODE_BF16_BIAS_RELU)
        bval = bias[col];
#pragma unroll
      for (int r = 0; r < 4; ++r) {
        int row = grow0 + i*16 + (lane>>4)*4 + r;
        float v = acc[i][j][r];
        if (MODE == MODE_F32_BIAS) {
          Cf[(size_t)row*ldc + col] = v + bval;
        } else if (MODE == MODE_F32_NOBIAS) {
          Cf[(size_t)row*ldc + col] = v;
        } else {
          v += bval;
          if (MODE == MODE_BF16_BIAS_RELU) v = fmaxf(v, 0.f);
          Ch[(size_t)row*ldc + col] = bf16b(v);
        }
      }
    }
  }
}

// ====== fused attention v2: in-kernel V transpose, P aliased onto Ks (72KB) ======
__global__ __launch_bounds__(256) void k_attn(
    const unsigned short* __restrict__ qkv,
    const unsigned short* __restrict__ biasb,
    unsigned short* __restrict__ O) {
  __shared__ unsigned short Qs[64*64];
  __shared__ unsigned short Ks[256*64];   // after QK^T, reused as Ps[64][256]
  __shared__ unsigned short Vs[64*256];
  unsigned short* Ps = Ks;
  int t = threadIdx.x, lane = t & 63, wid = t >> 6;
  int z = blockIdx.y, n = z / NH, h = z - n*NH;
  int m0 = blockIdx.x * 64;
  const unsigned short* Qb = qkv + (size_t)n*SEQ*QKVN + (size_t)h*DKH + (size_t)m0*QKVN;
  const unsigned short* Kb = qkv + (size_t)n*SEQ*QKVN + H + (size_t)h*DKH;
  const unsigned short* Vb = qkv + (size_t)n*SEQ*QKVN + 2*H + (size_t)h*DKH;
#pragma unroll
  for (int r = 0; r < 2; ++r) {
    int chunk = wid*2 + r;
    int row = chunk*8 + (lane >> 3);
    int col = ((lane & 7) ^ (row & 7)) * 8;
    gload16(Qb + (size_t)row*QKVN + col, &Qs[chunk*512]);
  }
#pragma unroll
  for (int r = 0; r < 8; ++r) {
    int chunk = wid*8 + r;
    int row = chunk*8 + (lane >> 3);
    int col = ((lane & 7) ^ (row & 7)) * 8;
    gload16(Kb + (size_t)row*QKVN + col, &Ks[chunk*512]);
  }
  {
    int kr0 = t >> 3, d0 = (t & 7) * 8;
#pragma unroll
    for (int i = 0; i < 8; ++i) {
      int k = kr0 + i*32;
      v8s vv = *(const v8s*)(Vb + (size_t)k*QKVN + d0);
      int kc = k >> 3, ke = k & 7;
#pragma unroll
      for (int j = 0; j < 8; ++j) {
        int d = d0 + j;
        Vs[d*256 + ((kc ^ (d & 7)) << 3) + ke] = (unsigned short)vv[j];
      }
    }
  }
  __syncthreads();

  v4f acc[16];
#pragma unroll
  for (int j = 0; j < 16; ++j) acc[j] = (v4f){0.f,0.f,0.f,0.f};
#pragma unroll
  for (int ks = 0; ks < 2; ++ks) {
    int arow = wid*16 + (lane & 15);
    int ac = (ks*4 + (lane >> 4)) ^ (arow & 7);
    v8bf af = *(const v8bf*)&Qs[arow*64 + ac*8];
#pragma unroll
    for (int j = 0; j < 16; ++j) {
      int brow = j*16 + (lane & 15);
      int bc = (ks*4 + (lane >> 4)) ^ (brow & 7);
      v8bf bf = *(const v8bf*)&Ks[brow*64 + bc*8];
      acc[j] = __builtin_amdgcn_mfma_f32_16x16x32_bf16(af, bf, acc[j], 0, 0, 0);
    }
  }

  int col = lane & 15, quad = lane >> 4;
  const unsigned short* bb = biasb + (size_t)n*65536;
  float e[16][4];
  float rm[4] = {-1e30f, -1e30f, -1e30f, -1e30f};
#pragma unroll
  for (int r = 0; r < 4; ++r) {
    int row = m0 + wid*16 + quad*4 + r;
#pragma unroll
    for (int j = 0; j < 16; ++j) {
      float v = acc[j][r]*0.125f + b2f(bb[(size_t)row*256 + j*16 + col]);
      e[j][r] = v;
      rm[r] = fmaxf(rm[r], v);
    }
  }
#pragma unroll
  for (int r = 0; r < 4; ++r)
#pragma unroll
    for (int m = 1; m < 16; m <<= 1) rm[r] = fmaxf(rm[r], __shfl_xor(rm[r], m, 64));
  float rs[4] = {0.f, 0.f, 0.f, 0.f};
#pragma unroll
  for (int r = 0; r < 4; ++r)
#pragma unroll
    for (int j = 0; j < 16; ++j) {
      float ev = __expf(e[j][r] - rm[r]);
      e[j][r] = ev;
      rs[r] += ev;
    }
#pragma unroll
  for (int r = 0; r < 4; ++r) {
#pragma unroll
    for (int m = 1; m < 16; m <<= 1) rs[r] += __shfl_xor(rs[r], m, 64);
    rs[r] = 1.0f/rs[r];
  }

  __syncthreads();   // all waves done reading Ks before P overwrites it

#pragma unroll
  for (int r = 0; r < 4; ++r) {
    int row = wid*16 + quad*4 + r;
#pragma unroll
    for (int j = 0; j < 16; ++j) {
      int cc = j*2 + (col >> 3);
      Ps[row*256 + ((cc ^ (row & 7))*8) + (col & 7)] = bf16b(e[j][r]*rs[r]);
    }
  }
  asm volatile("s_waitcnt lgkmcnt(0)" ::: "memory");
  __builtin_amdgcn_sched_barrier(0);

  v4f po[4];
#pragma unroll
  for (int j = 0; j < 4; ++j) po[j] = (v4f){0.f,0.f,0.f,0.f};
#pragma unroll
  for (int kk = 0; kk < 8; ++kk) {
    int arow = wid*16 + (lane & 15);
    int c = kk*4 + (lane >> 4);
    v8bf af = *(const v8bf*)&Ps[arow*256 + ((c ^ (arow & 7))*8)];
#pragma unroll
    for (int j = 0; j < 4; ++j) {
      int brow = j*16 + (lane & 15);
      v8bf bf = *(const v8bf*)&Vs[brow*256 + ((c ^ (brow & 7))*8)];
      po[j] = __builtin_amdgcn_mfma_f32_16x16x32_bf16(af, bf, po[j], 0, 0, 0);
    }
  }

  unsigned short* Ob = O + ((size_t)n*SEQ + m0)*H + (size_t)h*DKH;
#pragma unroll
  for (int j = 0; j < 4; ++j) {
    int ocol = j*16 + (lane & 15);
#pragma unroll
    for (int r = 0; r < 4; ++r) {
      int orow = wid*16 + quad*4 + r;
      Ob[(size_t)orow*H + ocol] = bf16b(po[j][r]);
    }
  }
}

// ============ weight transpose+cast ============
__global__ __launch_bounds__(256) void k_wT(const float* __restrict__ in,
                                            unsigned short* __restrict__ out,
                                            int Nn, int Kk) {
  int n0 = blockIdx.x*64, k0 = blockIdx.y*64;
  __shared__ float T[64][72];
  int t = threadIdx.x;
  int r = t >> 4, c4 = (t & 15) * 4;
#pragma unroll
  for (int i = 0; i < 4; ++i) {
    float4 v = *(const float4*)(in + (size_t)(k0 + r + i*16)*Nn + n0 + c4);
    T[c4+0][r+i*16] = v.x; T[c4+1][r+i*16] = v.y;
    T[c4+2][r+i*16] = v.z; T[c4+3][r+i*16] = v.w;
  }
  __syncthreads();
  int c = t >> 3, r8 = (t & 7) * 8;
#pragma unroll
  for (int i = 0; i < 2; ++i) {
    int cc = c + i*32;
    v8s o;
#pragma unroll
    for (int j = 0; j < 8; ++j) o[j] = (short)bf16b(T[cc][r8+j]);
    *(v8s*)(out + (size_t)(n0+cc)*Kk + k0 + r8) = o;
  }
}

__global__ void k_bqkv(const float* __restrict__ bq, const float* __restrict__ bk,
                       const float* __restrict__ bv, float* __restrict__ o) {
  int i = blockIdx.x*256 + threadIdx.x;
  if (i >= 3*QKVN) return;
  int l = i / QKVN, j = i - l*QKVN;
  float v = (j < H) ? bq[l*H + j] : (j < 2*H) ? bk[l*H + j - H] : bv[l*H + j - 2*H];
  o[i] = v;
}

__global__ __launch_bounds__(256) void k_cast(const float* __restrict__ x,
                                              float* __restrict__ enc,
                                              unsigned short* __restrict__ enc16) {
  size_t i = ((size_t)blockIdx.x*256 + threadIdx.x)*4;
  float4 v = *(const float4*)(x + i);
  *(float4*)(enc + i) = v;
  ushort4 u = { bf16b(v.x), bf16b(v.y), bf16b(v.z), bf16b(v.w) };
  *(ushort4*)(enc16 + i) = u;
}

__global__ __launch_bounds__(256) void k_fusion_weights(
    const float* __restrict__ x, const float* __restrict__ lin_w,
    const float* __restrict__ lin_b, float* __restrict__ wsoft) {
  int n = blockIdx.x, t = threadIdx.x;
  __shared__ float xm[H];
  __shared__ float sred[4];
  __shared__ float logits[12];
  if (t < 192) {
    const float4* p = (const float4*)(x + (size_t)n*SEQ*H) + t;
    float4 s = {0.f,0.f,0.f,0.f};
    for (int r = 0; r < SEQ; ++r) {
      float4 v = p[(size_t)r*192];
      s.x += v.x; s.y += v.y; s.z += v.z; s.w += v.w;
    }
    xm[t*4+0] = s.x*(1.0f/SEQ); xm[t*4+1] = s.y*(1.0f/SEQ);
    xm[t*4+2] = s.z*(1.0f/SEQ); xm[t*4+3] = s.w*(1.0f/SEQ);
  }
  __syncthreads();
  float lacc[12];
#pragma unroll
  for (int j = 0; j < 12; ++j) lacc[j] = 0.f;
  for (int hh = t; hh < H; hh += 256) {
    float xv = xm[hh];
#pragma unroll
    for (int j = 0; j < 12; ++j) lacc[j] += xv * lin_w[hh*12 + j];
  }
  for (int j = 0; j < 12; ++j) {
    float v = lacc[j];
#pragma unroll
    for (int m = 1; m < 64; m <<= 1) v += __shfl_xor(v, m, 64);
    if ((t & 63) == 0) sred[t >> 6] = v;
    __syncthreads();
    if (t == 0) logits[j] = sred[0]+sred[1]+sred[2]+sred[3] + lin_b[j];
    __syncthreads();
  }
  if (t < 3) {
    int l = t;
    float mx = -1e30f;
    for (int m = 0; m < 4; ++m) mx = fmaxf(mx, logits[l*4+m]);
    float e[4], s = 0.f;
    for (int m = 0; m < 4; ++m) { e[m] = expf(logits[l*4+m]-mx); s += e[m]; }
    for (int m = 0; m < 4; ++m) wsoft[(l*NSEQ + n)*4 + m] = e[m]/s;
  }
}

// mask fusion -> bf16 bias
__global__ __launch_bounds__(256) void k_bias(
    const float* __restrict__ cm, const float* __restrict__ dm,
    const float* __restrict__ ent, const float* __restrict__ sm,
    const float* __restrict__ wsoft, int l, unsigned short* __restrict__ bias) {
  int g = blockIdx.x*256 + threadIdx.x;
  int n = g >> 14;
  int k4 = g & 63;
  const float* w = wsoft + (l*NSEQ + n)*4;
  float w0 = w[0], w1 = w[1], w2 = w[2], w3 = w[3];
  float4 c = ((const float4*)cm)[g];
  float4 d = ((const float4*)dm)[g];
  float4 s = ((const float4*)sm)[g];
  float4 e = ((const float4*)(ent + (size_t)n*SEQ))[k4];
  ushort4 o;
  o.x = bf16b(w0*c.x + w1*d.x + w2*e.x + w3*s.x);
  o.y = bf16b(w0*c.y + w1*d.y + w2*e.y + w3*s.y);
  o.z = bf16b(w0*c.z + w1*d.z + w2*e.z + w3*s.z);
  o.w = bf16b(w0*c.w + w1*d.w + w2*e.w + w3*s.w);
  ((ushort4*)bias)[g] = o;
}

__global__ void k_nonpad(const int* __restrict__ ids, float* __restrict__ npad) {
  int i = blockIdx.x*256 + threadIdx.x;
  if (i < MROWS) npad[i] = (ids[i] != 1) ? 1.0f : 0.0f;
}

__global__ __launch_bounds__(256) void k_ln(
    const float* __restrict__ f, float* __restrict__ enc,
    unsigned short* __restrict__ enc16,
    const float* __restrict__ g, const float* __restrict__ b,
    const float* __restrict__ npad) {
  int r = blockIdx.x, t = threadIdx.x;
  size_t base = (size_t)r*H;
  float v0 = f[base+t]     + enc[base+t];
  float v1 = f[base+t+256] + enc[base+t+256];
  float v2 = f[base+t+512] + enc[base+t+512];
  __shared__ float sred[4];
  float s = v0+v1+v2;
#pragma unroll
  for (int m = 1; m < 64; m <<= 1) s += __shfl_xor(s, m, 64);
  if ((t & 63) == 0) sred[t >> 6] = s;
  __syncthreads();
  float mean = (sred[0]+sred[1]+sred[2]+sred[3]) * (1.0f/H);
  __syncthreads();
  float d0 = v0-mean, d1 = v1-mean, d2 = v2-mean;
  float ss = d0*d0 + d1*d1 + d2*d2;
#pragma unroll
  for (int m = 1; m < 64; m <<= 1) ss += __shfl_xor(ss, m, 64);
  if ((t & 63) == 0) sred[t >> 6] = ss;
  __syncthreads();
  float var = (sred[0]+sred[1]+sred[2]+sred[3]) * (1.0f/H);
  float rstd = 1.0f/sqrtf(var + 1e-5f);
  float npv = npad[r];
  float o0 = (g[t]    *d0*rstd + b[t]    )*npv;
  float o1 = (g[t+256]*d1*rstd + b[t+256])*npv;
  float o2 = (g[t+512]*d2*rstd + b[t+512])*npv;
  enc[base+t]     = o0; enc[base+t+256] = o1; enc[base+t+512] = o2;
  enc16[base+t]     = bf16b(o0);
  enc16[base+t+256] = bf16b(o1);
  enc16[base+t+512] = bf16b(o2);
}

__global__ __launch_bounds__(256) void k_ln4(
    const float* __restrict__ p, float* __restrict__ enc,
    unsigned short* __restrict__ enc16,
    const float* __restrict__ g, const float* __restrict__ b,
    const float* __restrict__ npad, const float* __restrict__ cbias) {
  int r = blockIdx.x, t = threadIdx.x;
  size_t base = (size_t)r*H;
  const size_t PS = (size_t)MROWS*H;
  float v0 = p[base+t]     + p[PS+base+t]     + p[2*PS+base+t]     + p[3*PS+base+t]     + cbias[t]     + enc[base+t];
  float v1 = p[base+t+256] + p[PS+base+t+256] + p[2*PS+base+t+256] + p[3*PS+base+t+256] + cbias[t+256] + enc[base+t+256];
  float v2 = p[base+t+512] + p[PS+base+t+512] + p[2*PS+base+t+512] + p[3*PS+base+t+512] + cbias[t+512] + enc[base+t+512];
  __shared__ float sred[4];
  float s = v0+v1+v2;
#pragma unroll
  for (int m = 1; m < 64; m <<= 1) s += __shfl_xor(s, m, 64);
  if ((t & 63) == 0) sred[t >> 6] = s;
  __syncthreads();
  float mean = (sred[0]+sred[1]+sred[2]+sred[3]) * (1.0f/H);
  __syncthreads();
  float d0 = v0-mean, d1 = v1-mean, d2 = v2-mean;
  float ss = d0*d0 + d1*d1 + d2*d2;
#pragma unroll
  for (int m = 1; m < 64; m <<= 1) ss += __shfl_xor(ss, m, 64);
  if ((t & 63) == 0) sred[t >> 6] = ss;
  __syncthreads();
  float var = (sred[0]+sred[1]+sred[2]+sred[3]) * (1.0f/H);
  float rstd = 1.0f/sqrtf(var + 1e-5f);
  float npv = npad[r];
  float o0 = (g[t]    *d0*rstd + b[t]    )*npv;
  float o1 = (g[t+256]*d1*rstd + b[t+256])*npv;
  float o2 = (g[t+512]*d2*rstd + b[t+512])*npv;
  enc[base+t]     = o0; enc[base+t+256] = o1; enc[base+t+512] = o2;
  enc16[base+t]     = bf16b(o0);
  enc16[base+t+256] = bf16b(o1);
  enc16[base+t+512] = bf16b(o2);
}

__global__ __launch_bounds__(256) void k_colstats(
    const float* __restrict__ enc, float* __restrict__ csum, float* __restrict__ csq) {
  int r0 = blockIdx.x*16, t = threadIdx.x;
  float s0=0,s1=0,s2=0,q0=0,q1=0,q2=0;
  for (int r = 0; r < 16; ++r) {
    const float* row = enc + (size_t)(r0+r)*H;
    float a = row[t], b = row[t+256], c = row[t+512];
    s0 += a; s1 += b; s2 += c;
    q0 += a*a; q1 += b*b; q2 += c*c;
  }
  atomicAdd(&csum[t],     s0); atomicAdd(&csum[t+256], s1); atomicAdd(&csum[t+512], s2);
  atomicAdd(&csq[t],      q0); atomicAdd(&csq[t+256],  q1); atomicAdd(&csq[t+512],  q2);
}

__global__ __launch_bounds__(256) void k_poolprep(
    const float* __restrict__ x, const float* __restrict__ enc,
    const float* __restrict__ csum, const float* __restrict__ csq,
    const float* __restrict__ bnt_g, const float* __restrict__ bnt_b,
    float* __restrict__ ps0) {
  int n = blockIdx.x, t = threadIdx.x;
  for (int hh = t; hh < H; hh += 256) {
    float m = csum[hh] * (1.0f/MROWS);
    float var = csq[hh] * (1.0f/MROWS) - m*m;
    float rstd = 1.0f/sqrtf(var + 1e-5f);
    float e = enc[(size_t)n*SEQ*H + hh];
    ps0[n*H + hh] = x[(size_t)n*SEQ*H + hh] + bnt_g[hh]*(e-m)*rstd + bnt_b[hh];
  }
}

__global__ __launch_bounds__(256) void k_poolmm(
    const float* __restrict__ ps0, const float* __restrict__ pool_w,
    const float* __restrict__ pool_b, float* __restrict__ pooled) {
  int n = blockIdx.y, jb = blockIdx.x*64;
  __shared__ float s0[H];
  __shared__ float part[4][64];
  int t = threadIdx.x;
  for (int hh = t; hh < H; hh += 256) s0[hh] = ps0[n*H + hh];
  __syncthreads();
  int j = t & 63, q = t >> 6;
  float a = 0.f;
  int h0 = q*192;
  for (int hh = h0; hh < h0+192; ++hh)
    a = fmaf(s0[hh], pool_w[(size_t)hh*H + jb + j], a);
  part[q][j] = a;
  __syncthreads();
  if (t < 64) {
    float v = part[0][t]+part[1][t]+part[2][t]+part[3][t] + pool_b[jb+t];
    pooled[n*H + jb + t] = tanhf(v);
  }
}

__global__ __launch_bounds__(256) void k_final(
    const float* __restrict__ pooled, const float* __restrict__ bn_g,
    const float* __restrict__ bn_b, const float* __restrict__ cls_w,
    const float* __restrict__ cls_b, float* __restrict__ out) {
  int t = threadIdx.x;
  float acc[16];
#pragma unroll
  for (int n = 0; n < 16; ++n) acc[n] = 0.f;
  for (int hh = t; hh < H; hh += 256) {
    float p[16]; float m = 0.f;
#pragma unroll
    for (int n = 0; n < 16; ++n) { p[n] = pooled[n*H + hh]; m += p[n]; }
    m *= (1.0f/16.f);
    float var = 0.f;
#pragma unroll
    for (int n = 0; n < 16; ++n) { float d = p[n]-m; var += d*d; }
    var *= (1.0f/16.f);
    float rstd = 1.0f/sqrtf(var + 1e-5f);
    float gw = bn_g[hh]*rstd*cls_w[hh];
    float off = bn_b[hh]*cls_w[hh];
#pragma unroll
    for (int n = 0; n < 16; ++n) acc[n] += (p[n]-m)*gw + off;
  }
  __shared__ float sred[4];
  for (int n = 0; n < 16; ++n) {
    float v = acc[n];
#pragma unroll
    for (int m = 1; m < 64; m <<= 1) v += __shfl_xor(v, m, 64);
    if ((t & 63) == 0) sred[t >> 6] = v;
    __syncthreads();
    if (t == 0) out[n] = sred[0]+sred[1]+sred[2]+sred[3] + cls_b[0];
    __syncthreads();
  }
}

extern "C" void kernel_launch(void* const* d_in, const int* in_sizes, int n_in,
                              void* d_out, int out_size, void* d_ws, size_t ws_size,
                              hipStream_t stream) {
  const int*   input_ids = (const int*)  d_in[0];
  const float* x       = (const float*)d_in[1];
  const float* cm      = (const float*)d_in[3];
  const float* dm      = (const float*)d_in[4];
  const float* ent     = (const float*)d_in[5];
  const float* sm      = (const float*)d_in[6];
  const float* lin_w   = (const float*)d_in[7];
  const float* lin_b   = (const float*)d_in[8];
  const float* Wq      = (const float*)d_in[9];
  const float* bq      = (const float*)d_in[10];
  const float* Wk      = (const float*)d_in[11];
  const float* bk      = (const float*)d_in[12];
  const float* Wv      = (const float*)d_in[13];
  const float* bv      = (const float*)d_in[14];
  const float* Wo      = (const float*)d_in[15];
  const float* bo      = (const float*)d_in[16];
  const float* ln1_g   = (const float*)d_in[17];
  const float* ln1_b   = (const float*)d_in[18];
  const float* W1      = (const float*)d_in[19];
  const float* b1      = (const float*)d_in[20];
  const float* W2      = (const float*)d_in[21];
  const float* b2      = (const float*)d_in[22];
  const float* ln2_g   = (const float*)d_in[23];
  const float* ln2_b   = (const float*)d_in[24];
  const float* bnt_g   = (const float*)d_in[25];
  const float* bnt_b   = (const float*)d_in[26];
  const float* pool_w  = (const float*)d_in[27];
  const float* pool_b  = (const float*)d_in[28];
  const float* bn_g    = (const float*)d_in[29];
  const float* bn_b    = (const float*)d_in[30];
  const float* cls_w   = (const float*)d_in[31];
  const float* cls_b   = (const float*)d_in[32];
  float* out = (float*)d_out;
  (void)ws_size; (void)n_in; (void)in_sizes; (void)out_size;

  char* wsb = (char*)d_ws;
  size_t off = 0;
  auto alloc = [&](size_t bytes) {
    void* p = (void*)(wsb + off);
    off += (bytes + 255) & ~(size_t)255;
    return p;
  };
  float* enc            = (float*)alloc((size_t)MROWS*H*4);
  unsigned short* enc16 = (unsigned short*)alloc((size_t)MROWS*H*2);
  unsigned short* qkv16 = (unsigned short*)alloc((size_t)MROWS*QKVN*2);
  unsigned short* ob16  = (unsigned short*)alloc((size_t)MROWS*H*2);
  float* fbuf           = (float*)alloc((size_t)4*MROWS*H*4);
  unsigned short* PH    = (unsigned short*)alloc((size_t)MROWS*DI*2);
  unsigned short* hidden16 = PH;
  unsigned short* biasb = (unsigned short*)alloc((size_t)NSEQ*SEQ*SEQ*2);
  unsigned short* WqkvT = (unsigned short*)alloc((size_t)3*QKVN*H*2);
  unsigned short* WoT   = (unsigned short*)alloc((size_t)3*H*H*2);
  unsigned short* W1T   = (unsigned short*)alloc((size_t)3*DI*H*2);
  unsigned short* W2T   = (unsigned short*)alloc((size_t)3*H*DI*2);
  float* bqkv   = (float*)alloc(3*QKVN*4);
  float* wsoft  = (float*)alloc(3*16*4*4);
  float* npad   = (float*)alloc(MROWS*4);
  float* csum   = (float*)alloc(H*4);
  float* csq    = (float*)alloc(H*4);
  float* ps0    = (float*)alloc(16*H*4);
  float* pooled = (float*)alloc(16*H*4);

  k_cast<<<MROWS*H/1024, 256, 0, stream>>>(x, enc, enc16);
  k_fusion_weights<<<16, 256, 0, stream>>>(x, lin_w, lin_b, wsoft);
  k_nonpad<<<MROWS/256, 256, 0, stream>>>(input_ids, npad);
  k_bqkv<<<27, 256, 0, stream>>>(bq, bk, bv, bqkv);
  for (int l = 0; l < 3; ++l) {
    k_wT<<<dim3(12,12), 256, 0, stream>>>(Wq + (size_t)l*H*H, WqkvT + (size_t)l*QKVN*H,           H, H);
    k_wT<<<dim3(12,12), 256, 0, stream>>>(Wk + (size_t)l*H*H, WqkvT + (size_t)l*QKVN*H + H*H,     H, H);
    k_wT<<<dim3(12,12), 256, 0, stream>>>(Wv + (size_t)l*H*H, WqkvT + (size_t)l*QKVN*H + 2*H*H,   H, H);
    k_wT<<<dim3(12,12), 256, 0, stream>>>(Wo + (size_t)l*H*H, WoT + (size_t)l*H*H,                H, H);
    k_wT<<<dim3(64,12), 256, 0, stream>>>(W1 + (size_t)l*H*DI, W1T + (size_t)l*DI*H,              DI, H);
    k_wT<<<dim3(12,64), 256, 0, stream>>>(W2 + (size_t)l*DI*H, W2T + (size_t)l*H*DI,              H, DI);
  }

  for (int l = 0; l < 3; ++l) {
    k_bias<<<1024, 256, 0, stream>>>(cm, dm, ent, sm, wsoft, l, biasb);
    // QKV: 128x128, BK=32, depth-2 counted
    k_mm<128,128,MODE_BF16_BIAS,32,2,true><<<dim3(18,32,1), 256, 0, stream>>>(
        enc16, H, 0, 0, WqkvT + (size_t)l*QKVN*H, H, 0, 0,
        qkv16, QKVN, 0, 0, bqkv + l*QKVN, H, 1);
    // fused attention v2 (in-kernel V^T, P aliases Ks, 72KB LDS)
    k_attn<<<dim3(4,192), 256, 0, stream>>>(qkv16, biasb, ob16);
    // Wo (64x64 BK=64 depth-3 + swizzle)
    k_mm<64,64,MODE_F32_BIAS,64,3,true><<<dim3(12,64,1), 256, 0, stream>>>(
        ob16, H, 0, 0, WoT + (size_t)l*H*H, H, 0, 0,
        fbuf, H, 0, 0, bo + l*H, H, 1);
    k_ln<<<MROWS, 256, 0, stream>>>(fbuf, enc, enc16, ln1_g + l*H, ln1_b + l*H, npad);
    // W1 + ReLU: 256x256 8-wave dbuf-counted
    k_mm256<MODE_BF16_BIAS_RELU><<<dim3(16,16), 512, 131072, stream>>>(
        enc16, H, W1T + (size_t)l*DI*H, H, hidden16, DI, b1 + l*DI, H);
    // W2: split-K4, 128x128, BK=32, depth-2 counted  [R9-proven config]
    k_mm<128,128,MODE_F32_NOBIAS,32,2,true><<<dim3(6,32,4), 256, 0, stream>>>(
        hidden16, DI, 0, 1024, W2T + (size_t)l*H*DI, DI, 0, 1024,
        fbuf, H, 0, (long long)MROWS*H, nullptr, 1024, 4);
    k_ln4<<<MROWS, 256, 0, stream>>>(fbuf, enc, enc16, ln2_g + l*H, ln2_b + l*H, npad, b2 + l*H);
  }

  hipMemsetAsync(csum, 0, H*sizeof(float), stream);
  hipMemsetAsync(csq,  0, H*sizeof(float), stream);
  k_colstats<<<256, 256, 0, stream>>>(enc, csum, csq);
  k_poolprep<<<16, 256, 0, stream>>>(x, enc, csum, csq, bnt_g, bnt_b, ps0);
  k_poolmm<<<dim3(12,16), 256, 0, stream>>>(ps0, pool_w, pool_b, pooled);
  k_final<<<1, 256, 0, stream>>>(pooled, bn_g, bn_b, cls_w, cls_b, out);
}